// Round 15
// baseline (612.425 us; speedup 1.0000x reference)
//
#include <hip/hip_runtime.h>
#include <hip/hip_bf16.h>

// Problem constants
#define PP 1568
#define TT 8
#define DD 196
#define HD 64
#define NBH 48
#define NROW (NBH*PP*TT)        // 602112 rows per tensor
#define RPW 32                  // rows per wave (one per lane-pair)
#define WPB 4                   // independent waves per block (no barriers)
#define ROWS_PB (RPW*WPB)       // 128
#define NBLK4 (NROW/ROWS_PB)    // 4704 blocks
#define NPART (NBLK4*WPB)       // 18816 partials
#define NRED1 ((NPART+255)/256) // 74
#define VSLAB (DD*TT*HD)        // floats per (b,h) v slab
#define BPB 98                  // blocks per bh (12544/128)
#define KMASK 0xFFFFFF00u

typedef float f4 __attribute__((ext_vector_type(4)));
typedef unsigned u4v __attribute__((ext_vector_type(4)));

__device__ __forceinline__ float readlane_f(float v, int l) {
    return __int_as_float(__builtin_amdgcn_readlane(__float_as_int(v), l));
}

__device__ __forceinline__ float wave_sum_u(float v) {
#define STEPS(ctrl) { float t_ = __int_as_float(__builtin_amdgcn_update_dpp( \
        0, __float_as_int(v), ctrl, 0xF, 0xF, true)); v += t_; }
    STEPS(0x111) STEPS(0x112) STEPS(0x114) STEPS(0x118) STEPS(0x142) STEPS(0x143)
#undef STEPS
    return readlane_f(v, 63);
}

__device__ __forceinline__ unsigned UMX(unsigned a, unsigned b){ return a>b?a:b; }
__device__ __forceinline__ unsigned UMN(unsigned a, unsigned b){ return a<b?a:b; }

// single-instruction unsigned median-of-3 (VOP3, gfx950; R13-proven)
__device__ __forceinline__ unsigned med3u(unsigned a, unsigned b, unsigned c) {
    unsigned d;
    asm("v_med3_u32 %0, %1, %2, %3" : "=v"(d) : "v"(a), "v"(b), "v"(c));
    return d;
}

// inverse of monotone float->u32 order transform (applied to key & KMASK)
__device__ __forceinline__ float untr(unsigned u) {
    return (u & 0x80000000u) ? __uint_as_float(u ^ 0x80000000u)
                             : __uint_as_float(~u);
}

// Named members, NOT arrays (R5: arrays -> LDS; R4: refs -> scratch).
struct K10 { unsigned k0,k1,k2,k3,k4,k5,k6,k7,k8,k9; };

// depth-10 med3 sorted-insert: z0=max(y0,c); zi=med3(y_{i-1},y_i,c).
// Depth 10 per half-row => top-10 of each half is EXACT => merged row
// top-10 is exact (a half cannot hold >10 of the top-10).
#define PUTK10(Q,X,D) { unsigned b_=__float_as_uint(X); \
  unsigned u_=b_^((unsigned)((int)b_>>31)|0x80000000u); \
  unsigned c_=(u_&KMASK)|(unsigned)(D); \
  unsigned n0_=UMX(Q.k0,c_); \
  unsigned n1_=med3u(Q.k0,Q.k1,c_); \
  unsigned n2_=med3u(Q.k1,Q.k2,c_); \
  unsigned n3_=med3u(Q.k2,Q.k3,c_); \
  unsigned n4_=med3u(Q.k3,Q.k4,c_); \
  unsigned n5_=med3u(Q.k4,Q.k5,c_); \
  unsigned n6_=med3u(Q.k5,Q.k6,c_); \
  unsigned n7_=med3u(Q.k6,Q.k7,c_); \
  unsigned n8_=med3u(Q.k7,Q.k8,c_); \
  unsigned n9_=med3u(Q.k8,Q.k9,c_); \
  Q.k0=n0_; Q.k1=n1_; Q.k2=n2_; Q.k3=n3_; Q.k4=n4_; \
  Q.k5=n5_; Q.k6=n6_; Q.k7=n7_; Q.k8=n8_; Q.k9=n9_; }
#define PUT4K10(Q,V,D0) PUTK10(Q,(V).x,(D0)) PUTK10(Q,(V).y,(D0)+1) \
                        PUTK10(Q,(V).z,(D0)+2) PUTK10(Q,(V).w,(D0)+3)

// lane's chain over its CONTIGUOUS half-row (even: bytes [0,400) of the row,
// odd: [400,784)). Contiguous per-lane regions = every fetched line fully
// used in a tight window -> no staging LDS needed and no 1.75GB over-fetch
// (R14's eighth-chain pattern straddled lines across a ~250-op window).
// Direction trick: even lanes walk forward, odd lanes backward, so both
// touchers of a lane-boundary-straddling line hit it in the same batch.
__device__ __forceinline__ K10 chain_half(const char* p, int dbase,
                                          int cbase, int cstep) {
    K10 q = {0,0,0,0,0,0,0,0,0,0};
#pragma unroll 1
    for (int b = 0; b < 6; ++b) {
        int c0 = cbase + cstep*(4*b);
        int c1 = c0 + cstep, c2 = c0 + 2*cstep, c3 = c0 + 3*cstep;
        f4 v0 = *(const f4*)(p + c0*16);
        f4 v1 = *(const f4*)(p + c1*16);
        f4 v2 = *(const f4*)(p + c2*16);
        f4 v3 = *(const f4*)(p + c3*16);
        PUT4K10(q, v0, dbase + 4*c0)
        PUT4K10(q, v1, dbase + 4*c1)
        PUT4K10(q, v2, dbase + 4*c2)
        PUT4K10(q, v3, dbase + 4*c3)
    }
    return q;
}

#define SWZ(x, pat) (unsigned)__builtin_amdgcn_ds_swizzle((int)(x), pat)
// xor1: partner lane within the pair
__device__ __forceinline__ K10 kshuf1(K10 a) {
    K10 r;
    r.k0=SWZ(a.k0,0x041F); r.k1=SWZ(a.k1,0x041F); r.k2=SWZ(a.k2,0x041F);
    r.k3=SWZ(a.k3,0x041F); r.k4=SWZ(a.k4,0x041F); r.k5=SWZ(a.k5,0x041F);
    r.k6=SWZ(a.k6,0x041F); r.k7=SWZ(a.k7,0x041F); r.k8=SWZ(a.k8,0x041F);
    r.k9=SWZ(a.k9,0x041F);
    return r;
}

// merge two sorted-desc 10-lists -> sorted-desc top-10 of union (R9-proven).
__device__ __forceinline__ K10 kmrg(K10 A, K10 B) {
    unsigned p00=UMN(A.k0,B.k0);
    unsigned p01=UMN(A.k0,B.k1), p10=UMN(A.k1,B.k0);
    unsigned p02=UMN(A.k0,B.k2), p11=UMN(A.k1,B.k1), p20=UMN(A.k2,B.k0);
    unsigned p03=UMN(A.k0,B.k3), p12=UMN(A.k1,B.k2), p21=UMN(A.k2,B.k1), p30=UMN(A.k3,B.k0);
    unsigned p04=UMN(A.k0,B.k4), p13=UMN(A.k1,B.k3), p22=UMN(A.k2,B.k2), p31=UMN(A.k3,B.k1), p40=UMN(A.k4,B.k0);
    unsigned p05=UMN(A.k0,B.k5), p14=UMN(A.k1,B.k4), p23=UMN(A.k2,B.k3), p32=UMN(A.k3,B.k2), p41=UMN(A.k4,B.k1), p50=UMN(A.k5,B.k0);
    unsigned p06=UMN(A.k0,B.k6), p15=UMN(A.k1,B.k5), p24=UMN(A.k2,B.k4), p33=UMN(A.k3,B.k3), p42=UMN(A.k4,B.k2), p51=UMN(A.k5,B.k1), p60=UMN(A.k6,B.k0);
    unsigned p07=UMN(A.k0,B.k7), p16=UMN(A.k1,B.k6), p25=UMN(A.k2,B.k5), p34=UMN(A.k3,B.k4), p43=UMN(A.k4,B.k3), p52=UMN(A.k5,B.k2), p61=UMN(A.k6,B.k1), p70=UMN(A.k7,B.k0);
    unsigned p08=UMN(A.k0,B.k8), p17=UMN(A.k1,B.k7), p26=UMN(A.k2,B.k6), p35=UMN(A.k3,B.k5), p44=UMN(A.k4,B.k4), p53=UMN(A.k5,B.k3), p62=UMN(A.k6,B.k2), p71=UMN(A.k7,B.k1), p80=UMN(A.k8,B.k0);
    K10 M;
    M.k0=UMX(A.k0,B.k0);
    M.k1=UMX(UMX(A.k1,B.k1),p00);
    M.k2=UMX(UMX(A.k2,B.k2),UMX(p01,p10));
    M.k3=UMX(UMX(A.k3,B.k3),UMX(p02,UMX(p11,p20)));
    M.k4=UMX(UMX(A.k4,B.k4),UMX(UMX(p03,p12),UMX(p21,p30)));
    M.k5=UMX(UMX(A.k5,B.k5),UMX(UMX(p04,p13),UMX(p22,UMX(p31,p40))));
    M.k6=UMX(UMX(A.k6,B.k6),UMX(UMX(p05,p14),UMX(UMX(p23,p32),UMX(p41,p50))));
    M.k7=UMX(UMX(A.k7,B.k7),UMX(UMX(UMX(p06,p15),UMX(p24,p33)),UMX(UMX(p42,p51),p60)));
    M.k8=UMX(UMX(A.k8,B.k8),UMX(UMX(UMX(p07,p16),UMX(p25,p34)),UMX(UMX(p43,p52),UMX(p61,p70))));
    M.k9=UMX(UMX(A.k9,B.k9),UMX(UMX(UMX(p08,p17),UMX(p26,p35)),UMX(UMX(p44,p53),UMX(UMX(p62,p71),p80))));
    return M;
}

// pack (weight,f-idx): weight's low 8 mantissa bits replaced by the d-index
// (rel err 2^-16, R13-proven)
#define PKW(F,K) ((__float_as_uint(F)&KMASK)|((K)&0xFFu))

__global__ __launch_bounds__(256) void vtop_main(
        const float* __restrict__ att_s, const float* __restrict__ att_t,
        const float* __restrict__ v_s,   const float* __restrict__ v_t,
        float* __restrict__ partial) {
    // per-wave private handoff only (no staging, no barriers): 2560 B/wave
    __shared__ u4v wbuf[WPB][5][RPW];    // 10240 B/block

    int tid  = threadIdx.x;
    int wid  = tid >> 6;
    int lane = tid & 63;
    int blk  = blockIdx.x;
    int bh   = blk / BPB;

    int oddl  = lane & 1;
    int row   = lane >> 1;                       // this pair's row (0..31)
    int hoff  = oddl ? 400 : 0;                  // byte offset of half
    int dbase = oddl ? 100 : 0;                  // element offset of half
    int cbase = oddl ? 23 : 0;                   // chunk walk start
    int cstep = oddl ? -1 : 1;                   //  ... and direction

    size_t rowoff = ((size_t)blk*ROWS_PB + wid*RPW + row) * (DD*4);
    const char* rowS = (const char*)att_s + rowoff + hoff;
    const char* rowT = (const char*)att_t + rowoff + hoff;

    // ---- chains: even lane elements [0,100), odd [100,196), depth-10 ----
    K10 qS = chain_half(rowS, dbase, cbase, cstep);
    if (!oddl) { f4 v = *(const f4*)(rowS + 384); PUT4K10(qS, v, 96) }
    K10 qT = chain_half(rowT, dbase, cbase, cstep);
    if (!oddl) { f4 v = *(const f4*)(rowT + 384); PUT4K10(qT, v, 96) }

    // ---- single xor1 merge -> exact row top-10 (both lanes hold it) ----
    K10 fS = kmrg(qS, kshuf1(qS));
    K10 fT = kmrg(qT, kshuf1(qT));

    // weights: shift by row max (= fS.k0 / fT.k0); softmax scale cancels
    float CS = untr(fS.k0 & KMASK), CT = untr(fT.k0 & KMASK);
    float wS0=__expf(untr(fS.k0&KMASK)-CS), wS1=__expf(untr(fS.k1&KMASK)-CS),
          wS2=__expf(untr(fS.k2&KMASK)-CS), wS3=__expf(untr(fS.k3&KMASK)-CS),
          wS4=__expf(untr(fS.k4&KMASK)-CS), wS5=__expf(untr(fS.k5&KMASK)-CS),
          wS6=__expf(untr(fS.k6&KMASK)-CS), wS7=__expf(untr(fS.k7&KMASK)-CS),
          wS8=__expf(untr(fS.k8&KMASK)-CS), wS9=__expf(untr(fS.k9&KMASK)-CS);
    float wT0=__expf(untr(fT.k0&KMASK)-CT), wT1=__expf(untr(fT.k1&KMASK)-CT),
          wT2=__expf(untr(fT.k2&KMASK)-CT), wT3=__expf(untr(fT.k3&KMASK)-CT),
          wT4=__expf(untr(fT.k4&KMASK)-CT), wT5=__expf(untr(fT.k5&KMASK)-CT),
          wT6=__expf(untr(fT.k6&KMASK)-CT), wT7=__expf(untr(fT.k7&KMASK)-CT),
          wT8=__expf(untr(fT.k8&KMASK)-CT), wT9=__expf(untr(fT.k9&KMASK)-CT);
    float wsS = (((wS0+wS1)+(wS2+wS3))+((wS4+wS5)+(wS6+wS7)))+(wS8+wS9);
    float wsT = (((wT0+wT1)+(wT2+wT3))+((wT4+wT5)+(wT6+wT7)))+(wT8+wT9);
    float invS =  __builtin_amdgcn_rcpf(wsS);
    float invT = -__builtin_amdgcn_rcpf(wsT);    // sign-fold: oS/wsS - oT/wsT

    if (!oddl) {                                 // even lane writes its row
        u4v w;
        w.x=PKW(wS0*invS,fS.k0); w.y=PKW(wS1*invS,fS.k1);
        w.z=PKW(wS2*invS,fS.k2); w.w=PKW(wS3*invS,fS.k3);
        wbuf[wid][0][row]=w;
        w.x=PKW(wS4*invS,fS.k4); w.y=PKW(wS5*invS,fS.k5);
        w.z=PKW(wS6*invS,fS.k6); w.w=PKW(wS7*invS,fS.k7);
        wbuf[wid][1][row]=w;
        w.x=PKW(wS8*invS,fS.k8); w.y=PKW(wS9*invS,fS.k9);
        w.z=PKW(wT0*invT,fT.k0); w.w=PKW(wT1*invT,fT.k1);
        wbuf[wid][2][row]=w;
        w.x=PKW(wT2*invT,fT.k2); w.y=PKW(wT3*invT,fT.k3);
        w.z=PKW(wT4*invT,fT.k4); w.w=PKW(wT5*invT,fT.k5);
        wbuf[wid][3][row]=w;
        w.x=PKW(wT6*invT,fT.k6); w.y=PKW(wT7*invT,fT.k7);
        w.z=PKW(wT8*invT,fT.k8); w.w=PKW(wT9*invT,fT.k9);
        wbuf[wid][4][row]=w;
    }

    // ---- wave-cooperative product: lane = output channel e ----
    const float* vSb = v_s + (size_t)bh * VSLAB;
    const float* vTb = v_t + (size_t)bh * VSLAB;
    float lacc = 0.f;
#pragma unroll 1
    for (int k = 0; k < RPW; ++k) {
        unsigned base = ((unsigned)(k & 7) << 6) + (unsigned)lane;  // t*64 + e
        u4v w0v=wbuf[wid][0][k], w1v=wbuf[wid][1][k], w2v=wbuf[wid][2][k],
            w3v=wbuf[wid][3][k], w4v=wbuf[wid][4][k];
        float dsum = 0.f;
#define TRM(U, VB) { unsigned u_=(U); \
        float wf_ = __uint_as_float(u_ & KMASK); \
        dsum = fmaf(wf_, VB[((u_ & 0xFFu) << 9) + base], dsum); }
        TRM(w0v.x, vSb) TRM(w0v.y, vSb) TRM(w0v.z, vSb) TRM(w0v.w, vSb)
        TRM(w1v.x, vSb) TRM(w1v.y, vSb) TRM(w1v.z, vSb) TRM(w1v.w, vSb)
        TRM(w2v.x, vSb) TRM(w2v.y, vSb)                     // S8,S9
        TRM(w2v.z, vTb) TRM(w2v.w, vTb)                     // T0,T1
        TRM(w3v.x, vTb) TRM(w3v.y, vTb) TRM(w3v.z, vTb) TRM(w3v.w, vTb)
        TRM(w4v.x, vTb) TRM(w4v.y, vTb) TRM(w4v.z, vTb) TRM(w4v.w, vTb)
#undef TRM
        lacc = fmaf(dsum, dsum, lacc);
    }

    float tot = wave_sum_u(lacc);
    if (lane == 0) partial[blk * WPB + wid] = tot;
}

// stage 1: 74 blocks x 256 -> 74 partials
__global__ __launch_bounds__(256) void vtop_reduce1(
        const float* __restrict__ partial, float* __restrict__ p2) {
    int i = blockIdx.x * 256 + threadIdx.x;
    float v = (i < NPART) ? partial[i] : 0.f;
    float wtot = wave_sum_u(v);
    __shared__ float sm[4];
    int lane = threadIdx.x & 63, wid = threadIdx.x >> 6;
    if (lane == 0) sm[wid] = wtot;
    __syncthreads();
    if (threadIdx.x == 0) p2[blockIdx.x] = (sm[0] + sm[1]) + (sm[2] + sm[3]);
}

// stage 2: single block over 74 values
__global__ __launch_bounds__(256) void vtop_reduce2(
        const float* __restrict__ p2, float* __restrict__ out) {
    __shared__ double smd[256];
    double a = 0.0;
    if (threadIdx.x < NRED1) a = (double)p2[threadIdx.x];
    smd[threadIdx.x] = a;
    __syncthreads();
    for (int s = 128; s > 0; s >>= 1) {
        if (threadIdx.x < s) smd[threadIdx.x] += smd[threadIdx.x + s];
        __syncthreads();
    }
    if (threadIdx.x == 0) {
        const double inv_n = 1.0 / ((double)NBH * PP * TT * HD);  // 1/38535168
        out[0] = (float)(smd[0] * inv_n);
    }
}

extern "C" void kernel_launch(void* const* d_in, const int* in_sizes, int n_in,
                              void* d_out, int out_size, void* d_ws, size_t ws_size,
                              hipStream_t stream) {
    const float* att_s = (const float*)d_in[0];
    const float* att_t = (const float*)d_in[1];
    const float* v_s   = (const float*)d_in[2];
    const float* v_t   = (const float*)d_in[3];
    float* out     = (float*)d_out;
    float* partial = (float*)d_ws;                 // NPART floats (~75 KB)
    float* p2      = (float*)d_ws + NPART;         // NRED1 floats

    vtop_main<<<NBLK4, 256, 0, stream>>>(att_s, att_t, v_s, v_t, partial);
    vtop_reduce1<<<NRED1, 256, 0, stream>>>(partial, p2);
    vtop_reduce2<<<1, 256, 0, stream>>>(p2, out);
}

// Round 16
// 331.042 us; speedup vs baseline: 1.8500x; 1.8500x over previous
//
#include <hip/hip_runtime.h>
#include <hip/hip_bf16.h>

// Problem constants
#define PP 1568
#define TT 8
#define DD 196
#define HD 64
#define NBH 48
#define NROW (NBH*PP*TT)        // 602112 rows per tensor
#define RPW 32                  // rows per wave
#define WPB 2                   // independent waves per block (no barriers)
#define NWAVE (NROW/RPW)        // 18816 waves total
#define NBLK5 (NWAVE/WPB)       // 9408 blocks
#define NXCD 8
#define CPX (NBLK5/NXCD)        // 1176 blocks per XCD chunk (exact)
#define NPART NWAVE             // 18816 partials
#define NRED1 ((NPART+255)/256) // 74
#define SUB (8*DD*4)            // 6272 B sub-slab (8 rows)
#define VSLAB (DD*TT*HD)        // floats per (b,h) v slab
#define WPBH 392                // waves per bh (12544 rows / 32)
#define KMASK 0xFFFFFF00u

typedef float f4 __attribute__((ext_vector_type(4)));
typedef unsigned u4v __attribute__((ext_vector_type(4)));

__device__ __forceinline__ float readlane_f(float v, int l) {
    return __int_as_float(__builtin_amdgcn_readlane(__float_as_int(v), l));
}

__device__ __forceinline__ float wave_sum_u(float v) {
#define STEPS(ctrl) { float t_ = __int_as_float(__builtin_amdgcn_update_dpp( \
        0, __float_as_int(v), ctrl, 0xF, 0xF, true)); v += t_; }
    STEPS(0x111) STEPS(0x112) STEPS(0x114) STEPS(0x118) STEPS(0x142) STEPS(0x143)
#undef STEPS
    return readlane_f(v, 63);
}

__device__ __forceinline__ unsigned UMX(unsigned a, unsigned b){ return a>b?a:b; }
__device__ __forceinline__ unsigned UMN(unsigned a, unsigned b){ return a<b?a:b; }

// single-instruction unsigned median-of-3 (VOP3, gfx950; R13-proven)
__device__ __forceinline__ unsigned med3u(unsigned a, unsigned b, unsigned c) {
    unsigned d;
    asm("v_med3_u32 %0, %1, %2, %3" : "=v"(d) : "v"(a), "v"(b), "v"(c));
    return d;
}

// inverse of monotone float->u32 order transform (applied to key & KMASK)
__device__ __forceinline__ float untr(unsigned u) {
    return (u & 0x80000000u) ? __uint_as_float(u ^ 0x80000000u)
                             : __uint_as_float(~u);
}

// Named members, NOT arrays (R5: arrays -> LDS; R4: refs -> scratch).
struct K6  { unsigned k0,k1,k2,k3,k4,k5; };
struct K10 { unsigned k0,k1,k2,k3,k4,k5,k6,k7,k8,k9; };
struct MR  { K10 f; unsigned mx; };

// med3 sorted-insert (R13-proven): y0'=max(y0,c); yi'=med3(y_{i-1},y_i,c).
// depth-6 (R10-proven: loss impact ~2e-5 << 4.8e-3 threshold).
#define PUTK6(Q,X,D) { unsigned b_=__float_as_uint(X); \
  unsigned u_=b_^((unsigned)((int)b_>>31)|0x80000000u); \
  unsigned c_=(u_&KMASK)|(unsigned)(D); \
  unsigned n0_=UMX(Q.k0,c_); \
  unsigned n1_=med3u(Q.k0,Q.k1,c_); \
  unsigned n2_=med3u(Q.k1,Q.k2,c_); \
  unsigned n3_=med3u(Q.k2,Q.k3,c_); \
  unsigned n4_=med3u(Q.k3,Q.k4,c_); \
  unsigned n5_=med3u(Q.k4,Q.k5,c_); \
  Q.k0=n0_; Q.k1=n1_; Q.k2=n2_; Q.k3=n3_; Q.k4=n4_; Q.k5=n5_; }
#define PUT4K6(Q,V,D0) PUTK6(Q,(V).x,(D0)) PUTK6(Q,(V).y,(D0)+1) \
                       PUTK6(Q,(V).z,(D0)+2) PUTK6(Q,(V).w,(D0)+3)

// lane's chain over its eighth of row a (from LDS staging — the ONLY pattern
// with clean 1.0GB fetch; all per-lane global streaming variants measured
// 1.75-1.89GB: R11/R14 eighth-chains, R15 contiguous half-rows)
__device__ __forceinline__ K6 chain_rows(const char* stg, int a, int b8) {
    K6 q = {0,0,0,0,0,0};
    const char* rb = stg + a*784 + b8*16;
    f4 v;
    v = *(const f4*)(rb);       PUT4K6(q, v, b8*4)
    v = *(const f4*)(rb+128);   PUT4K6(q, v, b8*4+32)
    v = *(const f4*)(rb+256);   PUT4K6(q, v, b8*4+64)
    v = *(const f4*)(rb+384);   PUT4K6(q, v, b8*4+96)
    v = *(const f4*)(rb+512);   PUT4K6(q, v, b8*4+128)
    v = *(const f4*)(rb+640);   PUT4K6(q, v, b8*4+160)
    if (b8 == 7) { v = *(const f4*)(stg + a*784 + 768); PUT4K6(q, v, 192) }
    return q;
}

#define SWZ(x, pat) (unsigned)__builtin_amdgcn_ds_swizzle((int)(x), pat)
__device__ __forceinline__ K6 kshuf8_6(K6 a) {
    K6 r;
    r.k0=SWZ(a.k0,0x201F); r.k1=SWZ(a.k1,0x201F); r.k2=SWZ(a.k2,0x201F);
    r.k3=SWZ(a.k3,0x201F); r.k4=SWZ(a.k4,0x201F); r.k5=SWZ(a.k5,0x201F);
    return r;
}
__device__ __forceinline__ K10 kshuf16(K10 a) {
    K10 r;
    r.k0=SWZ(a.k0,0x401F); r.k1=SWZ(a.k1,0x401F); r.k2=SWZ(a.k2,0x401F);
    r.k3=SWZ(a.k3,0x401F); r.k4=SWZ(a.k4,0x401F); r.k5=SWZ(a.k5,0x401F);
    r.k6=SWZ(a.k6,0x401F); r.k7=SWZ(a.k7,0x401F); r.k8=SWZ(a.k8,0x401F);
    r.k9=SWZ(a.k9,0x401F);
    return r;
}
__device__ __forceinline__ K10 kbp32(K10 a, int bpx) {
    K10 r;
    r.k0=(unsigned)__builtin_amdgcn_ds_bpermute(bpx,(int)a.k0);
    r.k1=(unsigned)__builtin_amdgcn_ds_bpermute(bpx,(int)a.k1);
    r.k2=(unsigned)__builtin_amdgcn_ds_bpermute(bpx,(int)a.k2);
    r.k3=(unsigned)__builtin_amdgcn_ds_bpermute(bpx,(int)a.k3);
    r.k4=(unsigned)__builtin_amdgcn_ds_bpermute(bpx,(int)a.k4);
    r.k5=(unsigned)__builtin_amdgcn_ds_bpermute(bpx,(int)a.k5);
    r.k6=(unsigned)__builtin_amdgcn_ds_bpermute(bpx,(int)a.k6);
    r.k7=(unsigned)__builtin_amdgcn_ds_bpermute(bpx,(int)a.k7);
    r.k8=(unsigned)__builtin_amdgcn_ds_bpermute(bpx,(int)a.k8);
    r.k9=(unsigned)__builtin_amdgcn_ds_bpermute(bpx,(int)a.k9);
    return r;
}

// merge two sorted-desc 6-lists -> sorted-desc top-10 of the 12-union.
__device__ __forceinline__ K10 kmrg66(K6 A, K6 B) {
    unsigned p00=UMN(A.k0,B.k0);
    unsigned p01=UMN(A.k0,B.k1), p10=UMN(A.k1,B.k0);
    unsigned p02=UMN(A.k0,B.k2), p11=UMN(A.k1,B.k1), p20=UMN(A.k2,B.k0);
    unsigned p03=UMN(A.k0,B.k3), p12=UMN(A.k1,B.k2), p21=UMN(A.k2,B.k1), p30=UMN(A.k3,B.k0);
    unsigned p04=UMN(A.k0,B.k4), p13=UMN(A.k1,B.k3), p22=UMN(A.k2,B.k2), p31=UMN(A.k3,B.k1), p40=UMN(A.k4,B.k0);
    unsigned p05=UMN(A.k0,B.k5), p14=UMN(A.k1,B.k4), p23=UMN(A.k2,B.k3), p32=UMN(A.k3,B.k2), p41=UMN(A.k4,B.k1), p50=UMN(A.k5,B.k0);
    unsigned p15=UMN(A.k1,B.k5), p24=UMN(A.k2,B.k4), p33=UMN(A.k3,B.k3), p42=UMN(A.k4,B.k2), p51=UMN(A.k5,B.k1);
    unsigned p25=UMN(A.k2,B.k5), p34=UMN(A.k3,B.k4), p43=UMN(A.k4,B.k3), p52=UMN(A.k5,B.k2);
    unsigned p35=UMN(A.k3,B.k5), p44=UMN(A.k4,B.k4), p53=UMN(A.k5,B.k3);
    K10 M;
    M.k0=UMX(A.k0,B.k0);
    M.k1=UMX(UMX(A.k1,B.k1),p00);
    M.k2=UMX(UMX(A.k2,B.k2),UMX(p01,p10));
    M.k3=UMX(UMX(A.k3,B.k3),UMX(p02,UMX(p11,p20)));
    M.k4=UMX(UMX(A.k4,B.k4),UMX(UMX(p03,p12),UMX(p21,p30)));
    M.k5=UMX(UMX(A.k5,B.k5),UMX(UMX(p04,p13),UMX(p22,UMX(p31,p40))));
    M.k6=UMX(UMX(p05,p14),UMX(UMX(p23,p32),UMX(p41,p50)));
    M.k7=UMX(UMX(p15,p24),UMX(p33,UMX(p42,p51)));
    M.k8=UMX(UMX(p25,p34),UMX(p43,p52));
    M.k9=UMX(p35,UMX(p44,p53));
    return M;
}

// merge two sorted-desc 10-lists -> sorted-desc top-10 of union.
__device__ __forceinline__ K10 kmrg(K10 A, K10 B) {
    unsigned p00=UMN(A.k0,B.k0);
    unsigned p01=UMN(A.k0,B.k1), p10=UMN(A.k1,B.k0);
    unsigned p02=UMN(A.k0,B.k2), p11=UMN(A.k1,B.k1), p20=UMN(A.k2,B.k0);
    unsigned p03=UMN(A.k0,B.k3), p12=UMN(A.k1,B.k2), p21=UMN(A.k2,B.k1), p30=UMN(A.k3,B.k0);
    unsigned p04=UMN(A.k0,B.k4), p13=UMN(A.k1,B.k3), p22=UMN(A.k2,B.k2), p31=UMN(A.k3,B.k1), p40=UMN(A.k4,B.k0);
    unsigned p05=UMN(A.k0,B.k5), p14=UMN(A.k1,B.k4), p23=UMN(A.k2,B.k3), p32=UMN(A.k3,B.k2), p41=UMN(A.k4,B.k1), p50=UMN(A.k5,B.k0);
    unsigned p06=UMN(A.k0,B.k6), p15=UMN(A.k1,B.k5), p24=UMN(A.k2,B.k4), p33=UMN(A.k3,B.k3), p42=UMN(A.k4,B.k2), p51=UMN(A.k5,B.k1), p60=UMN(A.k6,B.k0);
    unsigned p07=UMN(A.k0,B.k7), p16=UMN(A.k1,B.k6), p25=UMN(A.k2,B.k5), p34=UMN(A.k3,B.k4), p43=UMN(A.k4,B.k3), p52=UMN(A.k5,B.k2), p61=UMN(A.k6,B.k1), p70=UMN(A.k7,B.k0);
    unsigned p08=UMN(A.k0,B.k8), p17=UMN(A.k1,B.k7), p26=UMN(A.k2,B.k6), p35=UMN(A.k3,B.k5), p44=UMN(A.k4,B.k4), p53=UMN(A.k5,B.k3), p62=UMN(A.k6,B.k2), p71=UMN(A.k7,B.k1), p80=UMN(A.k8,B.k0);
    K10 M;
    M.k0=UMX(A.k0,B.k0);
    M.k1=UMX(UMX(A.k1,B.k1),p00);
    M.k2=UMX(UMX(A.k2,B.k2),UMX(p01,p10));
    M.k3=UMX(UMX(A.k3,B.k3),UMX(p02,UMX(p11,p20)));
    M.k4=UMX(UMX(A.k4,B.k4),UMX(UMX(p03,p12),UMX(p21,p30)));
    M.k5=UMX(UMX(A.k5,B.k5),UMX(UMX(p04,p13),UMX(p22,UMX(p31,p40))));
    M.k6=UMX(UMX(A.k6,B.k6),UMX(UMX(p05,p14),UMX(UMX(p23,p32),UMX(p41,p50))));
    M.k7=UMX(UMX(A.k7,B.k7),UMX(UMX(UMX(p06,p15),UMX(p24,p33)),UMX(UMX(p42,p51),p60)));
    M.k8=UMX(UMX(A.k8,B.k8),UMX(UMX(UMX(p07,p16),UMX(p25,p34)),UMX(UMX(p43,p52),UMX(p61,p70))));
    M.k9=UMX(UMX(A.k9,B.k9),UMX(UMX(UMX(p08,p17),UMX(p26,p35)),UMX(UMX(p44,p53),UMX(UMX(p62,p71),p80))));
    return M;
}

// eighth-chains -> row top-10 set + row max key
__device__ __forceinline__ MR merge_all(K6 q, int bpx) {
    K10 m = kmrg66(q, kshuf8_6(q));
    K10 n = kmrg(m, kshuf16(m));
    K10 r = kbp32(n, bpx);
    MR out;
    out.mx = UMX(n.k0, r.k0);
    out.f.k0=UMX(n.k0,r.k9); out.f.k1=UMX(n.k1,r.k8); out.f.k2=UMX(n.k2,r.k7);
    out.f.k3=UMX(n.k3,r.k6); out.f.k4=UMX(n.k4,r.k5); out.f.k5=UMX(n.k5,r.k4);
    out.f.k6=UMX(n.k6,r.k3); out.f.k7=UMX(n.k7,r.k2); out.f.k8=UMX(n.k8,r.k1);
    out.f.k9=UMX(n.k9,r.k0);
    return out;
}

#define LOADR(R, P) { const char* p_=(P); \
    R##0=*(const f4*)(p_+lane*16); \
    R##1=*(const f4*)(p_+1024+lane*16); \
    R##2=*(const f4*)(p_+2048+lane*16); \
    R##3=*(const f4*)(p_+3072+lane*16); \
    R##4=*(const f4*)(p_+4096+lane*16); \
    R##5=*(const f4*)(p_+5120+lane*16); \
    if (lane<8) R##6=*(const f4*)(p_+6144+lane*16); }
#define STORER(R) { \
    *(f4*)(stg+lane*16)=R##0; *(f4*)(stg+1024+lane*16)=R##1; \
    *(f4*)(stg+2048+lane*16)=R##2; *(f4*)(stg+3072+lane*16)=R##3; \
    *(f4*)(stg+4096+lane*16)=R##4; *(f4*)(stg+5120+lane*16)=R##5; \
    if (lane<8) *(f4*)(stg+6144+lane*16)=R##6; }

// pack (weight,f-idx): weight's low 8 mantissa bits replaced by the d-index
// (rel err 2^-16, R13-proven)
#define PKW(F,K) ((__float_as_uint(F)&KMASK)|((K)&0xFFu))

__global__ __launch_bounds__(128) void vtop_main(
        const float* __restrict__ att_s, const float* __restrict__ att_t,
        const float* __restrict__ v_s,   const float* __restrict__ v_t,
        float* __restrict__ partial) {
    // per-wave private LDS (no barriers): 6272+2560 = 8832 B/wave
    __shared__ f4  stgv[WPB][SUB/16];
    __shared__ u4v wbuf[WPB][5][RPW];

    int tid  = threadIdx.x;
    int wid  = tid >> 6;
    int lane = tid & 63;
    char* stg = (char*)&stgv[wid][0];
    int a = lane & 7, b8 = lane >> 3;
    int bpx = (lane ^ 32) << 2;

    // XCD-aware bijective swizzle (nwg = 9408 = 8*1176 exactly): XCD k gets
    // blocks [k*1176,(k+1)*1176) -> consecutive same-XCD blocks share bh ->
    // v slabs L2-resident per XCD.
    int blk = (blockIdx.x % NXCD) * CPX + blockIdx.x / NXCD;
    int gwave = blk * WPB + wid;               // global wave id (0..18815)
    int bh = gwave / WPBH;

    const char* baseS = (const char*)att_s + (size_t)gwave * (RPW*DD*4);
    const char* baseT = (const char*)att_t + (size_t)gwave * (RPW*DD*4);

    f4 rs0{},rs1{},rs2{},rs3{},rs4{},rs5{},rs6{};
    f4 rt0{},rt1{},rt2{},rt3{},rt4{},rt5{},rt6{};

    LOADR(rs, baseS)          // prologue: sub-slab 0 of S

#pragma unroll 1
    for (int s = 0; s < 4; ++s) {
        STORER(rs)                                     // S sub-slab -> LDS
        LOADR(rt, baseT + s*SUB)                       // T loads fly under chainS
        K6 qS = chain_rows(stg, a, b8);
        MR mS = merge_all(qS, bpx);
        STORER(rt)                                     // T -> LDS
        if (s < 3) LOADR(rs, baseS + (s+1)*SUB)        // next S under chainT
        K6 qT = chain_rows(stg, a, b8);
        MR mT = merge_all(qT, bpx);
        K10 fS = mS.f, fT = mT.f;

        // weights: shift by set max (softmax scale cancels in o/ws)
        float CS = untr(mS.mx & KMASK), CT = untr(mT.mx & KMASK);
        float wS0=__expf(untr(fS.k0&KMASK)-CS), wS1=__expf(untr(fS.k1&KMASK)-CS),
              wS2=__expf(untr(fS.k2&KMASK)-CS), wS3=__expf(untr(fS.k3&KMASK)-CS),
              wS4=__expf(untr(fS.k4&KMASK)-CS), wS5=__expf(untr(fS.k5&KMASK)-CS),
              wS6=__expf(untr(fS.k6&KMASK)-CS), wS7=__expf(untr(fS.k7&KMASK)-CS),
              wS8=__expf(untr(fS.k8&KMASK)-CS), wS9=__expf(untr(fS.k9&KMASK)-CS);
        float wT0=__expf(untr(fT.k0&KMASK)-CT), wT1=__expf(untr(fT.k1&KMASK)-CT),
              wT2=__expf(untr(fT.k2&KMASK)-CT), wT3=__expf(untr(fT.k3&KMASK)-CT),
              wT4=__expf(untr(fT.k4&KMASK)-CT), wT5=__expf(untr(fT.k5&KMASK)-CT),
              wT6=__expf(untr(fT.k6&KMASK)-CT), wT7=__expf(untr(fT.k7&KMASK)-CT),
              wT8=__expf(untr(fT.k8&KMASK)-CT), wT9=__expf(untr(fT.k9&KMASK)-CT);
        float wsS = (((wS0+wS1)+(wS2+wS3))+((wS4+wS5)+(wS6+wS7)))+(wS8+wS9);
        float wsT = (((wT0+wT1)+(wT2+wT3))+((wT4+wT5)+(wT6+wT7)))+(wT8+wT9);
        float invS =  __builtin_amdgcn_rcpf(wsS);
        float invT = -__builtin_amdgcn_rcpf(wsT);      // sign-fold: oS/wsS - oT/wsT

        if (lane < 8) {           // lane l holds row (s*8+l)'s results
            int row = (s << 3) | lane;
            u4v w;
            w.x=PKW(wS0*invS,fS.k0); w.y=PKW(wS1*invS,fS.k1);
            w.z=PKW(wS2*invS,fS.k2); w.w=PKW(wS3*invS,fS.k3);
            wbuf[wid][0][row]=w;
            w.x=PKW(wS4*invS,fS.k4); w.y=PKW(wS5*invS,fS.k5);
            w.z=PKW(wS6*invS,fS.k6); w.w=PKW(wS7*invS,fS.k7);
            wbuf[wid][1][row]=w;
            w.x=PKW(wS8*invS,fS.k8); w.y=PKW(wS9*invS,fS.k9);
            w.z=PKW(wT0*invT,fT.k0); w.w=PKW(wT1*invT,fT.k1);
            wbuf[wid][2][row]=w;
            w.x=PKW(wT2*invT,fT.k2); w.y=PKW(wT3*invT,fT.k3);
            w.z=PKW(wT4*invT,fT.k4); w.w=PKW(wT5*invT,fT.k5);
            wbuf[wid][3][row]=w;
            w.x=PKW(wT6*invT,fT.k6); w.y=PKW(wT7*invT,fT.k7);
            w.z=PKW(wT8*invT,fT.k8); w.w=PKW(wT9*invT,fT.k9);
            wbuf[wid][4][row]=w;
        }
    }

    // ---- wave-cooperative product: lane = output channel e ----
    const float* vSb = v_s + (size_t)bh * VSLAB;
    const float* vTb = v_t + (size_t)bh * VSLAB;
    float lacc = 0.f;
#pragma unroll 1
    for (int k = 0; k < RPW; ++k) {
        unsigned base = ((unsigned)(k & 7) << 6) + (unsigned)lane;  // t*64 + e
        u4v w0v=wbuf[wid][0][k], w1v=wbuf[wid][1][k], w2v=wbuf[wid][2][k],
            w3v=wbuf[wid][3][k], w4v=wbuf[wid][4][k];
        float dsum = 0.f;
#define TRM(U, VB) { unsigned u_=(U); \
        float wf_ = __uint_as_float(u_ & KMASK); \
        dsum = fmaf(wf_, VB[((u_ & 0xFFu) << 9) + base], dsum); }
        TRM(w0v.x, vSb) TRM(w0v.y, vSb) TRM(w0v.z, vSb) TRM(w0v.w, vSb)
        TRM(w1v.x, vSb) TRM(w1v.y, vSb) TRM(w1v.z, vSb) TRM(w1v.w, vSb)
        TRM(w2v.x, vSb) TRM(w2v.y, vSb)                     // S8,S9
        TRM(w2v.z, vTb) TRM(w2v.w, vTb)                     // T0,T1
        TRM(w3v.x, vTb) TRM(w3v.y, vTb) TRM(w3v.z, vTb) TRM(w3v.w, vTb)
        TRM(w4v.x, vTb) TRM(w4v.y, vTb) TRM(w4v.z, vTb) TRM(w4v.w, vTb)
#undef TRM
        lacc = fmaf(dsum, dsum, lacc);
    }

    float tot = wave_sum_u(lacc);
    if (lane == 0) partial[gwave] = tot;
}

// stage 1: 74 blocks x 256 -> 74 partials
__global__ __launch_bounds__(256) void vtop_reduce1(
        const float* __restrict__ partial, float* __restrict__ p2) {
    int i = blockIdx.x * 256 + threadIdx.x;
    float v = (i < NPART) ? partial[i] : 0.f;
    float wtot = wave_sum_u(v);
    __shared__ float sm[4];
    int lane = threadIdx.x & 63, wid = threadIdx.x >> 6;
    if (lane == 0) sm[wid] = wtot;
    __syncthreads();
    if (threadIdx.x == 0) p2[blockIdx.x] = (sm[0] + sm[1]) + (sm[2] + sm[3]);
}

// stage 2: single block over 74 values
__global__ __launch_bounds__(256) void vtop_reduce2(
        const float* __restrict__ p2, float* __restrict__ out) {
    __shared__ double smd[256];
    double a = 0.0;
    if (threadIdx.x < NRED1) a = (double)p2[threadIdx.x];
    smd[threadIdx.x] = a;
    __syncthreads();
    for (int s = 128; s > 0; s >>= 1) {
        if (threadIdx.x < s) smd[threadIdx.x] += smd[threadIdx.x + s];
        __syncthreads();
    }
    if (threadIdx.x == 0) {
        const double inv_n = 1.0 / ((double)NBH * PP * TT * HD);  // 1/38535168
        out[0] = (float)(smd[0] * inv_n);
    }
}

extern "C" void kernel_launch(void* const* d_in, const int* in_sizes, int n_in,
                              void* d_out, int out_size, void* d_ws, size_t ws_size,
                              hipStream_t stream) {
    const float* att_s = (const float*)d_in[0];
    const float* att_t = (const float*)d_in[1];
    const float* v_s   = (const float*)d_in[2];
    const float* v_t   = (const float*)d_in[3];
    float* out     = (float*)d_out;
    float* partial = (float*)d_ws;                 // NPART floats (~75 KB)
    float* p2      = (float*)d_ws + NPART;         // NRED1 floats

    vtop_main<<<NBLK5, 128, 0, stream>>>(att_s, att_t, v_s, v_t, partial);
    vtop_reduce1<<<NRED1, 256, 0, stream>>>(partial, p2);
    vtop_reduce2<<<1, 256, 0, stream>>>(p2, out);
}

// Round 17
// 323.734 us; speedup vs baseline: 1.8918x; 1.0226x over previous
//
#include <hip/hip_runtime.h>
#include <hip/hip_bf16.h>

// Problem constants
#define PP 1568
#define TT 8
#define DD 196
#define HD 64
#define NBH 48
#define NROW (NBH*PP*TT)        // 602112 rows per tensor
#define RPW 32                  // rows per wave
#define WPB 2                   // independent waves per block (no barriers)
#define NWAVE (NROW/RPW)        // 18816 waves total
#define NBLK5 (NWAVE/WPB)       // 9408 blocks
#define NXCD 8
#define CPX (NBLK5/NXCD)        // 1176 blocks per XCD chunk (exact)
#define NPART NWAVE             // 18816 partials
#define NRED1 ((NPART+255)/256) // 74
#define SUB (8*DD*4)            // 6272 B sub-slab (8 rows)
#define VSLAB (DD*TT*HD)        // floats per (b,h) v slab
#define WPBH 392                // waves per bh (12544 rows / 32)
#define KMASK 0xFFFFFF00u
#define NEG_INF (-3.0e38f)

typedef float f4 __attribute__((ext_vector_type(4)));
typedef unsigned u4v __attribute__((ext_vector_type(4)));

__device__ __forceinline__ float readlane_f(float v, int l) {
    return __int_as_float(__builtin_amdgcn_readlane(__float_as_int(v), l));
}

__device__ __forceinline__ float wave_sum_u(float v) {
#define STEPS(ctrl) { float t_ = __int_as_float(__builtin_amdgcn_update_dpp( \
        0, __float_as_int(v), ctrl, 0xF, 0xF, true)); v += t_; }
    STEPS(0x111) STEPS(0x112) STEPS(0x114) STEPS(0x118) STEPS(0x142) STEPS(0x143)
#undef STEPS
    return readlane_f(v, 63);
}

// value part of a packed key (low 8 mantissa bits = idx, zeroed)
__device__ __forceinline__ float kval(float k) {
    return __uint_as_float(__float_as_uint(k) & KMASK);
}

// Named members, NOT arrays (R5: arrays -> LDS; R4: refs -> scratch).
// FLOAT keys (R17): masking idx into the low mantissa bits preserves float
// order exactly (same bits, same compare order as the u32 transform in
// R13-R16 -> selection is bit-identical), but the 5-op monotone transform
// disappears: key pack is just and+or, compare chain uses v_max/med3_f32.
struct K6  { float k0,k1,k2,k3,k4,k5; };
struct K10 { float k0,k1,k2,k3,k4,k5,k6,k7,k8,k9; };
struct MR  { K10 f; float mx; };

// med3 sorted-insert (R13-proven, float form): y0'=max(y0,c);
// yi'=med3(y_{i-1},y_i,c). depth-6 (R10-proven: loss ~2e-5 << threshold).
#define PUTK6(Q,X,D) { \
  unsigned cu_=(__float_as_uint(X)&KMASK)|(unsigned)(D); \
  float c_=__uint_as_float(cu_); \
  float n0_=fmaxf(Q.k0,c_); \
  float n1_=__builtin_amdgcn_fmed3f(Q.k0,Q.k1,c_); \
  float n2_=__builtin_amdgcn_fmed3f(Q.k1,Q.k2,c_); \
  float n3_=__builtin_amdgcn_fmed3f(Q.k2,Q.k3,c_); \
  float n4_=__builtin_amdgcn_fmed3f(Q.k3,Q.k4,c_); \
  float n5_=__builtin_amdgcn_fmed3f(Q.k4,Q.k5,c_); \
  Q.k0=n0_; Q.k1=n1_; Q.k2=n2_; Q.k3=n3_; Q.k4=n4_; Q.k5=n5_; }
#define PUT4K6(Q,V,D0) PUTK6(Q,(V).x,(D0)) PUTK6(Q,(V).y,(D0)+1) \
                       PUTK6(Q,(V).z,(D0)+2) PUTK6(Q,(V).w,(D0)+3)

// lane's chain over its eighth of row a (from LDS staging — the ONLY pattern
// with clean fetch; all per-lane global streaming variants measured
// 1.75-1.89GB: R11/R14 eighth-chains, R15 contiguous half-rows)
__device__ __forceinline__ K6 chain_rows(const char* stg, int a, int b8) {
    K6 q = {NEG_INF,NEG_INF,NEG_INF,NEG_INF,NEG_INF,NEG_INF};
    const char* rb = stg + a*784 + b8*16;
    f4 v;
    v = *(const f4*)(rb);       PUT4K6(q, v, b8*4)
    v = *(const f4*)(rb+128);   PUT4K6(q, v, b8*4+32)
    v = *(const f4*)(rb+256);   PUT4K6(q, v, b8*4+64)
    v = *(const f4*)(rb+384);   PUT4K6(q, v, b8*4+96)
    v = *(const f4*)(rb+512);   PUT4K6(q, v, b8*4+128)
    v = *(const f4*)(rb+640);   PUT4K6(q, v, b8*4+160)
    if (b8 == 7) { f4 w = *(const f4*)(stg + a*784 + 768); PUT4K6(q, w, 192) }
    return q;
}

#define FSWZ(x, pat) __int_as_float(__builtin_amdgcn_ds_swizzle(__float_as_int(x), pat))
__device__ __forceinline__ K6 kshuf8_6(K6 a) {
    K6 r;
    r.k0=FSWZ(a.k0,0x201F); r.k1=FSWZ(a.k1,0x201F); r.k2=FSWZ(a.k2,0x201F);
    r.k3=FSWZ(a.k3,0x201F); r.k4=FSWZ(a.k4,0x201F); r.k5=FSWZ(a.k5,0x201F);
    return r;
}
__device__ __forceinline__ K10 kshuf16(K10 a) {
    K10 r;
    r.k0=FSWZ(a.k0,0x401F); r.k1=FSWZ(a.k1,0x401F); r.k2=FSWZ(a.k2,0x401F);
    r.k3=FSWZ(a.k3,0x401F); r.k4=FSWZ(a.k4,0x401F); r.k5=FSWZ(a.k5,0x401F);
    r.k6=FSWZ(a.k6,0x401F); r.k7=FSWZ(a.k7,0x401F); r.k8=FSWZ(a.k8,0x401F);
    r.k9=FSWZ(a.k9,0x401F);
    return r;
}
__device__ __forceinline__ float fbp(int bpx, float x) {
    return __int_as_float(__builtin_amdgcn_ds_bpermute(bpx, __float_as_int(x)));
}
__device__ __forceinline__ K10 kbp32(K10 a, int bpx) {
    K10 r;
    r.k0=fbp(bpx,a.k0); r.k1=fbp(bpx,a.k1); r.k2=fbp(bpx,a.k2);
    r.k3=fbp(bpx,a.k3); r.k4=fbp(bpx,a.k4); r.k5=fbp(bpx,a.k5);
    r.k6=fbp(bpx,a.k6); r.k7=fbp(bpx,a.k7); r.k8=fbp(bpx,a.k8);
    r.k9=fbp(bpx,a.k9);
    return r;
}

// merge two sorted-desc 6-lists -> sorted-desc top-10 of the 12-union.
__device__ __forceinline__ K10 kmrg66(K6 A, K6 B) {
    float p00=fminf(A.k0,B.k0);
    float p01=fminf(A.k0,B.k1), p10=fminf(A.k1,B.k0);
    float p02=fminf(A.k0,B.k2), p11=fminf(A.k1,B.k1), p20=fminf(A.k2,B.k0);
    float p03=fminf(A.k0,B.k3), p12=fminf(A.k1,B.k2), p21=fminf(A.k2,B.k1), p30=fminf(A.k3,B.k0);
    float p04=fminf(A.k0,B.k4), p13=fminf(A.k1,B.k3), p22=fminf(A.k2,B.k2), p31=fminf(A.k3,B.k1), p40=fminf(A.k4,B.k0);
    float p05=fminf(A.k0,B.k5), p14=fminf(A.k1,B.k4), p23=fminf(A.k2,B.k3), p32=fminf(A.k3,B.k2), p41=fminf(A.k4,B.k1), p50=fminf(A.k5,B.k0);
    float p15=fminf(A.k1,B.k5), p24=fminf(A.k2,B.k4), p33=fminf(A.k3,B.k3), p42=fminf(A.k4,B.k2), p51=fminf(A.k5,B.k1);
    float p25=fminf(A.k2,B.k5), p34=fminf(A.k3,B.k4), p43=fminf(A.k4,B.k3), p52=fminf(A.k5,B.k2);
    float p35=fminf(A.k3,B.k5), p44=fminf(A.k4,B.k4), p53=fminf(A.k5,B.k3);
    K10 M;
    M.k0=fmaxf(A.k0,B.k0);
    M.k1=fmaxf(fmaxf(A.k1,B.k1),p00);
    M.k2=fmaxf(fmaxf(A.k2,B.k2),fmaxf(p01,p10));
    M.k3=fmaxf(fmaxf(A.k3,B.k3),fmaxf(p02,fmaxf(p11,p20)));
    M.k4=fmaxf(fmaxf(A.k4,B.k4),fmaxf(fmaxf(p03,p12),fmaxf(p21,p30)));
    M.k5=fmaxf(fmaxf(A.k5,B.k5),fmaxf(fmaxf(p04,p13),fmaxf(p22,fmaxf(p31,p40))));
    M.k6=fmaxf(fmaxf(p05,p14),fmaxf(fmaxf(p23,p32),fmaxf(p41,p50)));
    M.k7=fmaxf(fmaxf(p15,p24),fmaxf(p33,fmaxf(p42,p51)));
    M.k8=fmaxf(fmaxf(p25,p34),fmaxf(p43,p52));
    M.k9=fmaxf(p35,fmaxf(p44,p53));
    return M;
}

// merge two sorted-desc 10-lists -> sorted-desc top-10 of union.
__device__ __forceinline__ K10 kmrg(K10 A, K10 B) {
    float p00=fminf(A.k0,B.k0);
    float p01=fminf(A.k0,B.k1), p10=fminf(A.k1,B.k0);
    float p02=fminf(A.k0,B.k2), p11=fminf(A.k1,B.k1), p20=fminf(A.k2,B.k0);
    float p03=fminf(A.k0,B.k3), p12=fminf(A.k1,B.k2), p21=fminf(A.k2,B.k1), p30=fminf(A.k3,B.k0);
    float p04=fminf(A.k0,B.k4), p13=fminf(A.k1,B.k3), p22=fminf(A.k2,B.k2), p31=fminf(A.k3,B.k1), p40=fminf(A.k4,B.k0);
    float p05=fminf(A.k0,B.k5), p14=fminf(A.k1,B.k4), p23=fminf(A.k2,B.k3), p32=fminf(A.k3,B.k2), p41=fminf(A.k4,B.k1), p50=fminf(A.k5,B.k0);
    float p06=fminf(A.k0,B.k6), p15=fminf(A.k1,B.k5), p24=fminf(A.k2,B.k4), p33=fminf(A.k3,B.k3), p42=fminf(A.k4,B.k2), p51=fminf(A.k5,B.k1), p60=fminf(A.k6,B.k0);
    float p07=fminf(A.k0,B.k7), p16=fminf(A.k1,B.k6), p25=fminf(A.k2,B.k5), p34=fminf(A.k3,B.k4), p43=fminf(A.k4,B.k3), p52=fminf(A.k5,B.k2), p61=fminf(A.k6,B.k1), p70=fminf(A.k7,B.k0);
    float p08=fminf(A.k0,B.k8), p17=fminf(A.k1,B.k7), p26=fminf(A.k2,B.k6), p35=fminf(A.k3,B.k5), p44=fminf(A.k4,B.k4), p53=fminf(A.k5,B.k3), p62=fminf(A.k6,B.k2), p71=fminf(A.k7,B.k1), p80=fminf(A.k8,B.k0);
    K10 M;
    M.k0=fmaxf(A.k0,B.k0);
    M.k1=fmaxf(fmaxf(A.k1,B.k1),p00);
    M.k2=fmaxf(fmaxf(A.k2,B.k2),fmaxf(p01,p10));
    M.k3=fmaxf(fmaxf(A.k3,B.k3),fmaxf(p02,fmaxf(p11,p20)));
    M.k4=fmaxf(fmaxf(A.k4,B.k4),fmaxf(fmaxf(p03,p12),fmaxf(p21,p30)));
    M.k5=fmaxf(fmaxf(A.k5,B.k5),fmaxf(fmaxf(p04,p13),fmaxf(p22,fmaxf(p31,p40))));
    M.k6=fmaxf(fmaxf(A.k6,B.k6),fmaxf(fmaxf(p05,p14),fmaxf(fmaxf(p23,p32),fmaxf(p41,p50))));
    M.k7=fmaxf(fmaxf(A.k7,B.k7),fmaxf(fmaxf(fmaxf(p06,p15),fmaxf(p24,p33)),fmaxf(fmaxf(p42,p51),p60)));
    M.k8=fmaxf(fmaxf(A.k8,B.k8),fmaxf(fmaxf(fmaxf(p07,p16),fmaxf(p25,p34)),fmaxf(fmaxf(p43,p52),fmaxf(p61,p70))));
    M.k9=fmaxf(fmaxf(A.k9,B.k9),fmaxf(fmaxf(fmaxf(p08,p17),fmaxf(p26,p35)),fmaxf(fmaxf(p44,p53),fmaxf(fmaxf(p62,p71),p80))));
    return M;
}

// eighth-chains -> row top-10 set + row max key
__device__ __forceinline__ MR merge_all(K6 q, int bpx) {
    K10 m = kmrg66(q, kshuf8_6(q));
    K10 n = kmrg(m, kshuf16(m));
    K10 r = kbp32(n, bpx);
    MR out;
    out.mx = fmaxf(n.k0, r.k0);
    out.f.k0=fmaxf(n.k0,r.k9); out.f.k1=fmaxf(n.k1,r.k8); out.f.k2=fmaxf(n.k2,r.k7);
    out.f.k3=fmaxf(n.k3,r.k6); out.f.k4=fmaxf(n.k4,r.k5); out.f.k5=fmaxf(n.k5,r.k4);
    out.f.k6=fmaxf(n.k6,r.k3); out.f.k7=fmaxf(n.k7,r.k2); out.f.k8=fmaxf(n.k8,r.k1);
    out.f.k9=fmaxf(n.k9,r.k0);
    return out;
}

#define LOADR(R, P) { const char* p_=(P); \
    R##0=*(const f4*)(p_+lane*16); \
    R##1=*(const f4*)(p_+1024+lane*16); \
    R##2=*(const f4*)(p_+2048+lane*16); \
    R##3=*(const f4*)(p_+3072+lane*16); \
    R##4=*(const f4*)(p_+4096+lane*16); \
    R##5=*(const f4*)(p_+5120+lane*16); \
    if (lane<8) R##6=*(const f4*)(p_+6144+lane*16); }
#define STORER(R) { \
    *(f4*)(stg+lane*16)=R##0; *(f4*)(stg+1024+lane*16)=R##1; \
    *(f4*)(stg+2048+lane*16)=R##2; *(f4*)(stg+3072+lane*16)=R##3; \
    *(f4*)(stg+4096+lane*16)=R##4; *(f4*)(stg+5120+lane*16)=R##5; \
    if (lane<8) *(f4*)(stg+6144+lane*16)=R##6; }

// pack (weight,f-idx): weight's low 8 mantissa bits replaced by the d-index
// (rel err 2^-16, R13-proven). Key K is a float key carrying idx in low bits.
#define PKW(F,K) ((__float_as_uint(F)&KMASK)|(__float_as_uint(K)&0xFFu))

__global__ __launch_bounds__(128) void vtop_main(
        const float* __restrict__ att_s, const float* __restrict__ att_t,
        const float* __restrict__ v_s,   const float* __restrict__ v_t,
        float* __restrict__ partial) {
    // per-wave private LDS (no barriers): 6272+2560 = 8832 B/wave
    __shared__ f4  stgv[WPB][SUB/16];
    __shared__ u4v wbuf[WPB][5][RPW];

    int tid  = threadIdx.x;
    int wid  = tid >> 6;
    int lane = tid & 63;
    char* stg = (char*)&stgv[wid][0];
    int a = lane & 7, b8 = lane >> 3;
    int bpx = (lane ^ 32) << 2;

    // XCD-aware bijective swizzle (nwg = 9408 = 8*1176 exactly) — R16-proven:
    // halved HBM fetch, best time so far.
    int blk = (blockIdx.x % NXCD) * CPX + blockIdx.x / NXCD;
    int gwave = blk * WPB + wid;               // global wave id (0..18815)
    int bh = gwave / WPBH;

    const char* baseS = (const char*)att_s + (size_t)gwave * (RPW*DD*4);
    const char* baseT = (const char*)att_t + (size_t)gwave * (RPW*DD*4);

    f4 rs0{},rs1{},rs2{},rs3{},rs4{},rs5{},rs6{};
    f4 rt0{},rt1{},rt2{},rt3{},rt4{},rt5{},rt6{};

    LOADR(rs, baseS)          // prologue: sub-slab 0 of S

#pragma unroll 1
    for (int s = 0; s < 4; ++s) {
        STORER(rs)                                     // S sub-slab -> LDS
        LOADR(rt, baseT + s*SUB)                       // T loads fly under chainS
        K6 qS = chain_rows(stg, a, b8);
        MR mS = merge_all(qS, bpx);
        STORER(rt)                                     // T -> LDS
        if (s < 3) LOADR(rs, baseS + (s+1)*SUB)        // next S under chainT
        K6 qT = chain_rows(stg, a, b8);
        MR mT = merge_all(qT, bpx);
        K10 fS = mS.f, fT = mT.f;

        // weights: shift by set max (softmax scale cancels in o/ws)
        float CS = kval(mS.mx), CT = kval(mT.mx);
        float wS0=__expf(kval(fS.k0)-CS), wS1=__expf(kval(fS.k1)-CS),
              wS2=__expf(kval(fS.k2)-CS), wS3=__expf(kval(fS.k3)-CS),
              wS4=__expf(kval(fS.k4)-CS), wS5=__expf(kval(fS.k5)-CS),
              wS6=__expf(kval(fS.k6)-CS), wS7=__expf(kval(fS.k7)-CS),
              wS8=__expf(kval(fS.k8)-CS), wS9=__expf(kval(fS.k9)-CS);
        float wT0=__expf(kval(fT.k0)-CT), wT1=__expf(kval(fT.k1)-CT),
              wT2=__expf(kval(fT.k2)-CT), wT3=__expf(kval(fT.k3)-CT),
              wT4=__expf(kval(fT.k4)-CT), wT5=__expf(kval(fT.k5)-CT),
              wT6=__expf(kval(fT.k6)-CT), wT7=__expf(kval(fT.k7)-CT),
              wT8=__expf(kval(fT.k8)-CT), wT9=__expf(kval(fT.k9)-CT);
        float wsS = (((wS0+wS1)+(wS2+wS3))+((wS4+wS5)+(wS6+wS7)))+(wS8+wS9);
        float wsT = (((wT0+wT1)+(wT2+wT3))+((wT4+wT5)+(wT6+wT7)))+(wT8+wT9);
        float invS =  __builtin_amdgcn_rcpf(wsS);
        float invT = -__builtin_amdgcn_rcpf(wsT);      // sign-fold: oS/wsS - oT/wsT

        if (lane < 8) {           // lane l holds row (s*8+l)'s results
            int row = (s << 3) | lane;
            u4v w;
            w.x=PKW(wS0*invS,fS.k0); w.y=PKW(wS1*invS,fS.k1);
            w.z=PKW(wS2*invS,fS.k2); w.w=PKW(wS3*invS,fS.k3);
            wbuf[wid][0][row]=w;
            w.x=PKW(wS4*invS,fS.k4); w.y=PKW(wS5*invS,fS.k5);
            w.z=PKW(wS6*invS,fS.k6); w.w=PKW(wS7*invS,fS.k7);
            wbuf[wid][1][row]=w;
            w.x=PKW(wS8*invS,fS.k8); w.y=PKW(wS9*invS,fS.k9);
            w.z=PKW(wT0*invT,fT.k0); w.w=PKW(wT1*invT,fT.k1);
            wbuf[wid][2][row]=w;
            w.x=PKW(wT2*invT,fT.k2); w.y=PKW(wT3*invT,fT.k3);
            w.z=PKW(wT4*invT,fT.k4); w.w=PKW(wT5*invT,fT.k5);
            wbuf[wid][3][row]=w;
            w.x=PKW(wT6*invT,fT.k6); w.y=PKW(wT7*invT,fT.k7);
            w.z=PKW(wT8*invT,fT.k8); w.w=PKW(wT9*invT,fT.k9);
            wbuf[wid][4][row]=w;
        }
    }

    // ---- wave-cooperative product: lane = output channel e ----
    // Packed (w|idx) values are wave-uniform per row -> readfirstlane moves
    // them to SGPRs; weight rides an SGPR operand of the fma, address math
    // runs on the SALU, vaddr is just lane*4. TRM: ~6 VALU -> 2.
    const float* vSb = v_s + (size_t)bh * VSLAB;
    const float* vTb = v_t + (size_t)bh * VSLAB;
    unsigned ul = (unsigned)lane;
    float lacc = 0.f;
#pragma unroll 1
    for (int k = 0; k < RPW; ++k) {
        unsigned t64 = ((unsigned)(k & 7) << 6);
        const float* vSk = vSb + t64;
        const float* vTk = vTb + t64;
        u4v w0v=wbuf[wid][0][k], w1v=wbuf[wid][1][k], w2v=wbuf[wid][2][k],
            w3v=wbuf[wid][3][k], w4v=wbuf[wid][4][k];
        float d0=0.f, d1=0.f, d2=0.f, d3=0.f;   // 4-way split: 5-deep chains
#define TRM(U, VB, ACC) { unsigned pk_=(unsigned)__builtin_amdgcn_readfirstlane((int)(U)); \
        float wf_ = __uint_as_float(pk_ & KMASK); \
        ACC = fmaf(wf_, VB[((pk_ & 0xFFu) << 9) + ul], ACC); }
        TRM(w0v.x, vSk, d0) TRM(w0v.y, vSk, d1) TRM(w0v.z, vSk, d2) TRM(w0v.w, vSk, d3)
        TRM(w1v.x, vSk, d0) TRM(w1v.y, vSk, d1) TRM(w1v.z, vSk, d2) TRM(w1v.w, vSk, d3)
        TRM(w2v.x, vSk, d0) TRM(w2v.y, vSk, d1)                     // S8,S9
        TRM(w2v.z, vTk, d2) TRM(w2v.w, vTk, d3)                     // T0,T1
        TRM(w3v.x, vTk, d0) TRM(w3v.y, vTk, d1) TRM(w3v.z, vTk, d2) TRM(w3v.w, vTk, d3)
        TRM(w4v.x, vTk, d0) TRM(w4v.y, vTk, d1) TRM(w4v.z, vTk, d2) TRM(w4v.w, vTk, d3)
#undef TRM
        float dsum = (d0 + d1) + (d2 + d3);
        lacc = fmaf(dsum, dsum, lacc);
    }

    float tot = wave_sum_u(lacc);
    if (lane == 0) partial[gwave] = tot;
}

// stage 1: 74 blocks x 256 -> 74 partials
__global__ __launch_bounds__(256) void vtop_reduce1(
        const float* __restrict__ partial, float* __restrict__ p2) {
    int i = blockIdx.x * 256 + threadIdx.x;
    float v = (i < NPART) ? partial[i] : 0.f;
    float wtot = wave_sum_u(v);
    __shared__ float sm[4];
    int lane = threadIdx.x & 63, wid = threadIdx.x >> 6;
    if (lane == 0) sm[wid] = wtot;
    __syncthreads();
    if (threadIdx.x == 0) p2[blockIdx.x] = (sm[0] + sm[1]) + (sm[2] + sm[3]);
}

// stage 2: single block over 74 values
__global__ __launch_bounds__(256) void vtop_reduce2(
        const float* __restrict__ p2, float* __restrict__ out) {
    __shared__ double smd[256];
    double a = 0.0;
    if (threadIdx.x < NRED1) a = (double)p2[threadIdx.x];
    smd[threadIdx.x] = a;
    __syncthreads();
    for (int s = 128; s > 0; s >>= 1) {
        if (threadIdx.x < s) smd[threadIdx.x] += smd[threadIdx.x + s];
        __syncthreads();
    }
    if (threadIdx.x == 0) {
        const double inv_n = 1.0 / ((double)NBH * PP * TT * HD);  // 1/38535168
        out[0] = (float)(smd[0] * inv_n);
    }
}

extern "C" void kernel_launch(void* const* d_in, const int* in_sizes, int n_in,
                              void* d_out, int out_size, void* d_ws, size_t ws_size,
                              hipStream_t stream) {
    const float* att_s = (const float*)d_in[0];
    const float* att_t = (const float*)d_in[1];
    const float* v_s   = (const float*)d_in[2];
    const float* v_t   = (const float*)d_in[3];
    float* out     = (float*)d_out;
    float* partial = (float*)d_ws;                 // NPART floats (~75 KB)
    float* p2      = (float*)d_ws + NPART;         // NRED1 floats

    vtop_main<<<NBLK5, 128, 0, stream>>>(att_s, att_t, v_s, v_t, partial);
    vtop_reduce1<<<NRED1, 256, 0, stream>>>(partial, p2);
    vtop_reduce2<<<1, 256, 0, stream>>>(p2, out);
}

// Round 18
// 323.046 us; speedup vs baseline: 1.8958x; 1.0021x over previous
//
#include <hip/hip_runtime.h>
#include <hip/hip_bf16.h>

// Problem constants
#define PP 1568
#define TT 8
#define DD 196
#define HD 64
#define NBH 48
#define NROW (NBH*PP*TT)        // 602112 rows per tensor
#define RPW 32                  // rows per wave
#define WPB 2                   // independent waves per block (no barriers)
#define NWAVE (NROW/RPW)        // 18816 waves total
#define NBLK5 (NWAVE/WPB)       // 9408 blocks
#define NXCD 8
#define CPX (NBLK5/NXCD)        // 1176 blocks per XCD chunk (exact)
#define NPART NWAVE             // 18816 partials
#define NRED1 ((NPART+255)/256) // 74
#define SUB (8*DD*4)            // 6272 B sub-slab (8 rows)
#define VSLAB (DD*TT*HD)        // floats per (b,h) v slab
#define WPBH 392                // waves per bh (12544 rows / 32)
#define KMASK 0xFFFFFF00u
#define NEG_INF (-3.0e38f)

typedef float f4 __attribute__((ext_vector_type(4)));
typedef unsigned u4v __attribute__((ext_vector_type(4)));

__device__ __forceinline__ float readlane_f(float v, int l) {
    return __int_as_float(__builtin_amdgcn_readlane(__float_as_int(v), l));
}

__device__ __forceinline__ float wave_sum_u(float v) {
#define STEPS(ctrl) { float t_ = __int_as_float(__builtin_amdgcn_update_dpp( \
        0, __float_as_int(v), ctrl, 0xF, 0xF, true)); v += t_; }
    STEPS(0x111) STEPS(0x112) STEPS(0x114) STEPS(0x118) STEPS(0x142) STEPS(0x143)
#undef STEPS
    return readlane_f(v, 63);
}

// value part of a packed key (low 8 mantissa bits = idx, zeroed)
__device__ __forceinline__ float kval(float k) {
    return __uint_as_float(__float_as_uint(k) & KMASK);
}

// async HBM -> LDS, 16B per lane (R18): staging data never visits VGPRs.
// Dest is wave-uniform base + lane*16 (exactly our layout); src is per-lane.
__device__ __forceinline__ void gload_lds(const void* g, void* l) {
    __builtin_amdgcn_global_load_lds(
        (const __attribute__((address_space(1))) unsigned*)g,
        (__attribute__((address_space(3))) unsigned*)l, 16, 0, 0);
}

// Named members, NOT arrays (R5: arrays -> LDS; R4: refs -> scratch).
// FLOAT keys (R17-proven): idx masked into low mantissa bits preserves float
// order exactly; chain uses v_max/med3_f32, pack is and+or.
struct K6  { float k0,k1,k2,k3,k4,k5; };
struct K10 { float k0,k1,k2,k3,k4,k5,k6,k7,k8,k9; };
struct MR  { K10 f; float mx; };

// med3 sorted-insert (R13-proven): y0'=max(y0,c); yi'=med3(y_{i-1},y_i,c).
// depth-6 (R10-proven: loss ~2e-5 << threshold).
#define PUTK6(Q,X,D) { \
  unsigned cu_=(__float_as_uint(X)&KMASK)|(unsigned)(D); \
  float c_=__uint_as_float(cu_); \
  float n0_=fmaxf(Q.k0,c_); \
  float n1_=__builtin_amdgcn_fmed3f(Q.k0,Q.k1,c_); \
  float n2_=__builtin_amdgcn_fmed3f(Q.k1,Q.k2,c_); \
  float n3_=__builtin_amdgcn_fmed3f(Q.k2,Q.k3,c_); \
  float n4_=__builtin_amdgcn_fmed3f(Q.k3,Q.k4,c_); \
  float n5_=__builtin_amdgcn_fmed3f(Q.k4,Q.k5,c_); \
  Q.k0=n0_; Q.k1=n1_; Q.k2=n2_; Q.k3=n3_; Q.k4=n4_; Q.k5=n5_; }
#define PUT4K6(Q,V,D0) PUTK6(Q,(V).x,(D0)) PUTK6(Q,(V).y,(D0)+1) \
                       PUTK6(Q,(V).z,(D0)+2) PUTK6(Q,(V).w,(D0)+3)

// lane's chain over its eighth of row a (from LDS staging — the ONLY pattern
// with clean fetch; per-lane global streaming measured 1.75-1.89GB:
// R11/R14 eighth-chains, R15 contiguous half-rows)
__device__ __forceinline__ K6 chain_rows(const char* stg, int a, int b8) {
    K6 q = {NEG_INF,NEG_INF,NEG_INF,NEG_INF,NEG_INF,NEG_INF};
    const char* rb = stg + a*784 + b8*16;
    f4 v;
    v = *(const f4*)(rb);       PUT4K6(q, v, b8*4)
    v = *(const f4*)(rb+128);   PUT4K6(q, v, b8*4+32)
    v = *(const f4*)(rb+256);   PUT4K6(q, v, b8*4+64)
    v = *(const f4*)(rb+384);   PUT4K6(q, v, b8*4+96)
    v = *(const f4*)(rb+512);   PUT4K6(q, v, b8*4+128)
    v = *(const f4*)(rb+640);   PUT4K6(q, v, b8*4+160)
    if (b8 == 7) { f4 w = *(const f4*)(stg + a*784 + 768); PUT4K6(q, w, 192) }
    return q;
}

#define FSWZ(x, pat) __int_as_float(__builtin_amdgcn_ds_swizzle(__float_as_int(x), pat))
__device__ __forceinline__ K6 kshuf8_6(K6 a) {
    K6 r;
    r.k0=FSWZ(a.k0,0x201F); r.k1=FSWZ(a.k1,0x201F); r.k2=FSWZ(a.k2,0x201F);
    r.k3=FSWZ(a.k3,0x201F); r.k4=FSWZ(a.k4,0x201F); r.k5=FSWZ(a.k5,0x201F);
    return r;
}
__device__ __forceinline__ K10 kshuf16(K10 a) {
    K10 r;
    r.k0=FSWZ(a.k0,0x401F); r.k1=FSWZ(a.k1,0x401F); r.k2=FSWZ(a.k2,0x401F);
    r.k3=FSWZ(a.k3,0x401F); r.k4=FSWZ(a.k4,0x401F); r.k5=FSWZ(a.k5,0x401F);
    r.k6=FSWZ(a.k6,0x401F); r.k7=FSWZ(a.k7,0x401F); r.k8=FSWZ(a.k8,0x401F);
    r.k9=FSWZ(a.k9,0x401F);
    return r;
}
__device__ __forceinline__ float fbp(int bpx, float x) {
    return __int_as_float(__builtin_amdgcn_ds_bpermute(bpx, __float_as_int(x)));
}
__device__ __forceinline__ K10 kbp32(K10 a, int bpx) {
    K10 r;
    r.k0=fbp(bpx,a.k0); r.k1=fbp(bpx,a.k1); r.k2=fbp(bpx,a.k2);
    r.k3=fbp(bpx,a.k3); r.k4=fbp(bpx,a.k4); r.k5=fbp(bpx,a.k5);
    r.k6=fbp(bpx,a.k6); r.k7=fbp(bpx,a.k7); r.k8=fbp(bpx,a.k8);
    r.k9=fbp(bpx,a.k9);
    return r;
}

// merge two sorted-desc 6-lists -> sorted-desc top-10 of the 12-union.
__device__ __forceinline__ K10 kmrg66(K6 A, K6 B) {
    float p00=fminf(A.k0,B.k0);
    float p01=fminf(A.k0,B.k1), p10=fminf(A.k1,B.k0);
    float p02=fminf(A.k0,B.k2), p11=fminf(A.k1,B.k1), p20=fminf(A.k2,B.k0);
    float p03=fminf(A.k0,B.k3), p12=fminf(A.k1,B.k2), p21=fminf(A.k2,B.k1), p30=fminf(A.k3,B.k0);
    float p04=fminf(A.k0,B.k4), p13=fminf(A.k1,B.k3), p22=fminf(A.k2,B.k2), p31=fminf(A.k3,B.k1), p40=fminf(A.k4,B.k0);
    float p05=fminf(A.k0,B.k5), p14=fminf(A.k1,B.k4), p23=fminf(A.k2,B.k3), p32=fminf(A.k3,B.k2), p41=fminf(A.k4,B.k1), p50=fminf(A.k5,B.k0);
    float p15=fminf(A.k1,B.k5), p24=fminf(A.k2,B.k4), p33=fminf(A.k3,B.k3), p42=fminf(A.k4,B.k2), p51=fminf(A.k5,B.k1);
    float p25=fminf(A.k2,B.k5), p34=fminf(A.k3,B.k4), p43=fminf(A.k4,B.k3), p52=fminf(A.k5,B.k2);
    float p35=fminf(A.k3,B.k5), p44=fminf(A.k4,B.k4), p53=fminf(A.k5,B.k3);
    K10 M;
    M.k0=fmaxf(A.k0,B.k0);
    M.k1=fmaxf(fmaxf(A.k1,B.k1),p00);
    M.k2=fmaxf(fmaxf(A.k2,B.k2),fmaxf(p01,p10));
    M.k3=fmaxf(fmaxf(A.k3,B.k3),fmaxf(p02,fmaxf(p11,p20)));
    M.k4=fmaxf(fmaxf(A.k4,B.k4),fmaxf(fmaxf(p03,p12),fmaxf(p21,p30)));
    M.k5=fmaxf(fmaxf(A.k5,B.k5),fmaxf(fmaxf(p04,p13),fmaxf(p22,fmaxf(p31,p40))));
    M.k6=fmaxf(fmaxf(p05,p14),fmaxf(fmaxf(p23,p32),fmaxf(p41,p50)));
    M.k7=fmaxf(fmaxf(p15,p24),fmaxf(p33,fmaxf(p42,p51)));
    M.k8=fmaxf(fmaxf(p25,p34),fmaxf(p43,p52));
    M.k9=fmaxf(p35,fmaxf(p44,p53));
    return M;
}

// merge two sorted-desc 10-lists -> sorted-desc top-10 of union.
__device__ __forceinline__ K10 kmrg(K10 A, K10 B) {
    float p00=fminf(A.k0,B.k0);
    float p01=fminf(A.k0,B.k1), p10=fminf(A.k1,B.k0);
    float p02=fminf(A.k0,B.k2), p11=fminf(A.k1,B.k1), p20=fminf(A.k2,B.k0);
    float p03=fminf(A.k0,B.k3), p12=fminf(A.k1,B.k2), p21=fminf(A.k2,B.k1), p30=fminf(A.k3,B.k0);
    float p04=fminf(A.k0,B.k4), p13=fminf(A.k1,B.k3), p22=fminf(A.k2,B.k2), p31=fminf(A.k3,B.k1), p40=fminf(A.k4,B.k0);
    float p05=fminf(A.k0,B.k5), p14=fminf(A.k1,B.k4), p23=fminf(A.k2,B.k3), p32=fminf(A.k3,B.k2), p41=fminf(A.k4,B.k1), p50=fminf(A.k5,B.k0);
    float p06=fminf(A.k0,B.k6), p15=fminf(A.k1,B.k5), p24=fminf(A.k2,B.k4), p33=fminf(A.k3,B.k3), p42=fminf(A.k4,B.k2), p51=fminf(A.k5,B.k1), p60=fminf(A.k6,B.k0);
    float p07=fminf(A.k0,B.k7), p16=fminf(A.k1,B.k6), p25=fminf(A.k2,B.k5), p34=fminf(A.k3,B.k4), p43=fminf(A.k4,B.k3), p52=fminf(A.k5,B.k2), p61=fminf(A.k6,B.k1), p70=fminf(A.k7,B.k0);
    float p08=fminf(A.k0,B.k8), p17=fminf(A.k1,B.k7), p26=fminf(A.k2,B.k6), p35=fminf(A.k3,B.k5), p44=fminf(A.k4,B.k4), p53=fminf(A.k5,B.k3), p62=fminf(A.k6,B.k2), p71=fminf(A.k7,B.k1), p80=fminf(A.k8,B.k0);
    K10 M;
    M.k0=fmaxf(A.k0,B.k0);
    M.k1=fmaxf(fmaxf(A.k1,B.k1),p00);
    M.k2=fmaxf(fmaxf(A.k2,B.k2),fmaxf(p01,p10));
    M.k3=fmaxf(fmaxf(A.k3,B.k3),fmaxf(p02,fmaxf(p11,p20)));
    M.k4=fmaxf(fmaxf(A.k4,B.k4),fmaxf(fmaxf(p03,p12),fmaxf(p21,p30)));
    M.k5=fmaxf(fmaxf(A.k5,B.k5),fmaxf(fmaxf(p04,p13),fmaxf(p22,fmaxf(p31,p40))));
    M.k6=fmaxf(fmaxf(A.k6,B.k6),fmaxf(fmaxf(p05,p14),fmaxf(fmaxf(p23,p32),fmaxf(p41,p50))));
    M.k7=fmaxf(fmaxf(A.k7,B.k7),fmaxf(fmaxf(fmaxf(p06,p15),fmaxf(p24,p33)),fmaxf(fmaxf(p42,p51),p60)));
    M.k8=fmaxf(fmaxf(A.k8,B.k8),fmaxf(fmaxf(fmaxf(p07,p16),fmaxf(p25,p34)),fmaxf(fmaxf(p43,p52),fmaxf(p61,p70))));
    M.k9=fmaxf(fmaxf(A.k9,B.k9),fmaxf(fmaxf(fmaxf(p08,p17),fmaxf(p26,p35)),fmaxf(fmaxf(p44,p53),fmaxf(fmaxf(p62,p71),p80))));
    return M;
}

// eighth-chains -> row top-10 set + row max key
__device__ __forceinline__ MR merge_all(K6 q, int bpx) {
    K10 m = kmrg66(q, kshuf8_6(q));
    K10 n = kmrg(m, kshuf16(m));
    K10 r = kbp32(n, bpx);
    MR out;
    out.mx = fmaxf(n.k0, r.k0);
    out.f.k0=fmaxf(n.k0,r.k9); out.f.k1=fmaxf(n.k1,r.k8); out.f.k2=fmaxf(n.k2,r.k7);
    out.f.k3=fmaxf(n.k3,r.k6); out.f.k4=fmaxf(n.k4,r.k5); out.f.k5=fmaxf(n.k5,r.k4);
    out.f.k6=fmaxf(n.k6,r.k3); out.f.k7=fmaxf(n.k7,r.k2); out.f.k8=fmaxf(n.k8,r.k1);
    out.f.k9=fmaxf(n.k9,r.k0);
    return out;
}

// stage one 6272B sub-slab HBM -> LDS (7 async copies, no VGPR round trip)
#define STAGE(SRC) { const char* s_=(SRC); \
    gload_lds(s_ +         (size_t)lane*16, stg); \
    gload_lds(s_ + 1024 +  (size_t)lane*16, stg+1024); \
    gload_lds(s_ + 2048 +  (size_t)lane*16, stg+2048); \
    gload_lds(s_ + 3072 +  (size_t)lane*16, stg+3072); \
    gload_lds(s_ + 4096 +  (size_t)lane*16, stg+4096); \
    gload_lds(s_ + 5120 +  (size_t)lane*16, stg+5120); \
    if (lane < 8) gload_lds(s_ + 6144 + (size_t)lane*16, stg+6144); }
#define WAITV asm volatile("s_waitcnt vmcnt(0)" ::: "memory");

// pack (weight,f-idx): weight's low 8 mantissa bits replaced by the d-index
// (rel err 2^-16, R13-proven). Key K is a float key carrying idx in low bits.
#define PKW(F,K) ((__float_as_uint(F)&KMASK)|(__float_as_uint(K)&0xFFu))

__global__ __launch_bounds__(128) void vtop_main(
        const float* __restrict__ att_s, const float* __restrict__ att_t,
        const float* __restrict__ v_s,   const float* __restrict__ v_t,
        float* __restrict__ partial) {
    // per-wave private LDS (no barriers): 6272+2560 = 8832 B/wave
    __shared__ f4  stgv[WPB][SUB/16];
    __shared__ u4v wbuf[WPB][5][RPW];

    int tid  = threadIdx.x;
    int wid  = tid >> 6;
    int lane = tid & 63;
    char* stg = (char*)&stgv[wid][0];
    int a = lane & 7, b8 = lane >> 3;
    int bpx = (lane ^ 32) << 2;

    // XCD-aware bijective swizzle (nwg = 9408 = 8*1176 exactly) — R16-proven:
    // halved HBM fetch, best time so far.
    int blk = (blockIdx.x % NXCD) * CPX + blockIdx.x / NXCD;
    int gwave = blk * WPB + wid;               // global wave id (0..18815)
    int bh = gwave / WPBH;

    const char* baseS = (const char*)att_s + (size_t)gwave * (RPW*DD*4);
    const char* baseT = (const char*)att_t + (size_t)gwave * (RPW*DD*4);

    STAGE(baseS)              // prologue: sub-slab 0 of S

#pragma unroll 1
    for (int s = 0; s < 4; ++s) {
        WAITV
        K6 qS = chain_rows(stg, a, b8);        // ds_reads all consumed here
        STAGE(baseT + s*SUB)                   // T latency hides under mergeS
        MR mS = merge_all(qS, bpx);
        K10 fS = mS.f;
        // S weights while T flies
        float CS = kval(mS.mx);
        float wS0=__expf(kval(fS.k0)-CS), wS1=__expf(kval(fS.k1)-CS),
              wS2=__expf(kval(fS.k2)-CS), wS3=__expf(kval(fS.k3)-CS),
              wS4=__expf(kval(fS.k4)-CS), wS5=__expf(kval(fS.k5)-CS),
              wS6=__expf(kval(fS.k6)-CS), wS7=__expf(kval(fS.k7)-CS),
              wS8=__expf(kval(fS.k8)-CS), wS9=__expf(kval(fS.k9)-CS);
        float wsS = (((wS0+wS1)+(wS2+wS3))+((wS4+wS5)+(wS6+wS7)))+(wS8+wS9);
        float invS = __builtin_amdgcn_rcpf(wsS);

        WAITV
        K6 qT = chain_rows(stg, a, b8);
        if (s < 3) STAGE(baseS + (s+1)*SUB)    // next S hides under mergeT
        MR mT = merge_all(qT, bpx);
        K10 fT = mT.f;
        float CT = kval(mT.mx);
        float wT0=__expf(kval(fT.k0)-CT), wT1=__expf(kval(fT.k1)-CT),
              wT2=__expf(kval(fT.k2)-CT), wT3=__expf(kval(fT.k3)-CT),
              wT4=__expf(kval(fT.k4)-CT), wT5=__expf(kval(fT.k5)-CT),
              wT6=__expf(kval(fT.k6)-CT), wT7=__expf(kval(fT.k7)-CT),
              wT8=__expf(kval(fT.k8)-CT), wT9=__expf(kval(fT.k9)-CT);
        float wsT = (((wT0+wT1)+(wT2+wT3))+((wT4+wT5)+(wT6+wT7)))+(wT8+wT9);
        float invT = -__builtin_amdgcn_rcpf(wsT);  // sign-fold: oS/wsS - oT/wsT

        if (lane < 8) {           // lane l holds row (s*8+l)'s results
            int row = (s << 3) | lane;
            u4v w;
            w.x=PKW(wS0*invS,fS.k0); w.y=PKW(wS1*invS,fS.k1);
            w.z=PKW(wS2*invS,fS.k2); w.w=PKW(wS3*invS,fS.k3);
            wbuf[wid][0][row]=w;
            w.x=PKW(wS4*invS,fS.k4); w.y=PKW(wS5*invS,fS.k5);
            w.z=PKW(wS6*invS,fS.k6); w.w=PKW(wS7*invS,fS.k7);
            wbuf[wid][1][row]=w;
            w.x=PKW(wS8*invS,fS.k8); w.y=PKW(wS9*invS,fS.k9);
            w.z=PKW(wT0*invT,fT.k0); w.w=PKW(wT1*invT,fT.k1);
            wbuf[wid][2][row]=w;
            w.x=PKW(wT2*invT,fT.k2); w.y=PKW(wT3*invT,fT.k3);
            w.z=PKW(wT4*invT,fT.k4); w.w=PKW(wT5*invT,fT.k5);
            wbuf[wid][3][row]=w;
            w.x=PKW(wT6*invT,fT.k6); w.y=PKW(wT7*invT,fT.k7);
            w.z=PKW(wT8*invT,fT.k8); w.w=PKW(wT9*invT,fT.k9);
            wbuf[wid][4][row]=w;
        }
    }

    // ---- wave-cooperative product: lane = output channel e ----
    // (w|idx) values are wave-uniform per row -> readfirstlane to SGPRs;
    // weight rides an SGPR fma operand, address math on SALU (R17-proven).
    const float* vSb = v_s + (size_t)bh * VSLAB;
    const float* vTb = v_t + (size_t)bh * VSLAB;
    unsigned ul = (unsigned)lane;
    float lacc = 0.f;
#pragma unroll 1
    for (int k = 0; k < RPW; ++k) {
        unsigned t64 = ((unsigned)(k & 7) << 6);
        const float* vSk = vSb + t64;
        const float* vTk = vTb + t64;
        u4v w0v=wbuf[wid][0][k], w1v=wbuf[wid][1][k], w2v=wbuf[wid][2][k],
            w3v=wbuf[wid][3][k], w4v=wbuf[wid][4][k];
        float d0=0.f, d1=0.f, d2=0.f, d3=0.f;   // 4-way split: 5-deep chains
#define TRM(U, VB, ACC) { unsigned pk_=(unsigned)__builtin_amdgcn_readfirstlane((int)(U)); \
        float wf_ = __uint_as_float(pk_ & KMASK); \
        ACC = fmaf(wf_, VB[((pk_ & 0xFFu) << 9) + ul], ACC); }
        TRM(w0v.x, vSk, d0) TRM(w0v.y, vSk, d1) TRM(w0v.z, vSk, d2) TRM(w0v.w, vSk, d3)
        TRM(w1v.x, vSk, d0) TRM(w1v.y, vSk, d1) TRM(w1v.z, vSk, d2) TRM(w1v.w, vSk, d3)
        TRM(w2v.x, vSk, d0) TRM(w2v.y, vSk, d1)                     // S8,S9
        TRM(w2v.z, vTk, d2) TRM(w2v.w, vTk, d3)                     // T0,T1
        TRM(w3v.x, vTk, d0) TRM(w3v.y, vTk, d1) TRM(w3v.z, vTk, d2) TRM(w3v.w, vTk, d3)
        TRM(w4v.x, vTk, d0) TRM(w4v.y, vTk, d1) TRM(w4v.z, vTk, d2) TRM(w4v.w, vTk, d3)
#undef TRM
        float dsum = (d0 + d1) + (d2 + d3);
        lacc = fmaf(dsum, dsum, lacc);
    }

    float tot = wave_sum_u(lacc);
    if (lane == 0) partial[gwave] = tot;
}

// stage 1: 74 blocks x 256 -> 74 partials
__global__ __launch_bounds__(256) void vtop_reduce1(
        const float* __restrict__ partial, float* __restrict__ p2) {
    int i = blockIdx.x * 256 + threadIdx.x;
    float v = (i < NPART) ? partial[i] : 0.f;
    float wtot = wave_sum_u(v);
    __shared__ float sm[4];
    int lane = threadIdx.x & 63, wid = threadIdx.x >> 6;
    if (lane == 0) sm[wid] = wtot;
    __syncthreads();
    if (threadIdx.x == 0) p2[blockIdx.x] = (sm[0] + sm[1]) + (sm[2] + sm[3]);
}

// stage 2: single block over 74 values
__global__ __launch_bounds__(256) void vtop_reduce2(
        const float* __restrict__ p2, float* __restrict__ out) {
    __shared__ double smd[256];
    double a = 0.0;
    if (threadIdx.x < NRED1) a = (double)p2[threadIdx.x];
    smd[threadIdx.x] = a;
    __syncthreads();
    for (int s = 128; s > 0; s >>= 1) {
        if (threadIdx.x < s) smd[threadIdx.x] += smd[threadIdx.x + s];
        __syncthreads();
    }
    if (threadIdx.x == 0) {
        const double inv_n = 1.0 / ((double)NBH * PP * TT * HD);  // 1/38535168
        out[0] = (float)(smd[0] * inv_n);
    }
}

extern "C" void kernel_launch(void* const* d_in, const int* in_sizes, int n_in,
                              void* d_out, int out_size, void* d_ws, size_t ws_size,
                              hipStream_t stream) {
    const float* att_s = (const float*)d_in[0];
    const float* att_t = (const float*)d_in[1];
    const float* v_s   = (const float*)d_in[2];
    const float* v_t   = (const float*)d_in[3];
    float* out     = (float*)d_out;
    float* partial = (float*)d_ws;                 // NPART floats (~75 KB)
    float* p2      = (float*)d_ws + NPART;         // NRED1 floats

    vtop_main<<<NBLK5, 128, 0, stream>>>(att_s, att_t, v_s, v_t, partial);
    vtop_reduce1<<<NRED1, 256, 0, stream>>>(partial, p2);
    vtop_reduce2<<<1, 256, 0, stream>>>(p2, out);
}

// Round 19
// 307.847 us; speedup vs baseline: 1.9894x; 1.0494x over previous
//
#include <hip/hip_runtime.h>
#include <hip/hip_bf16.h>

// Problem constants
#define PP 1568
#define TT 8
#define DD 196
#define HD 64
#define NBH 48
#define NROW (NBH*PP*TT)        // 602112 rows per tensor
#define RPW 32                  // rows per wave
#define WPB 2                   // independent waves per block (no barriers)
#define NWAVE (NROW/RPW)        // 18816 waves total
#define NBLK5 (NWAVE/WPB)       // 9408 blocks
#define NXCD 8
#define CPX (NBLK5/NXCD)        // 1176 blocks per XCD chunk (exact)
#define NPART NWAVE             // 18816 partials
#define NRED1 ((NPART+255)/256) // 74
#define SUB (8*DD*4)            // 6272 B sub-slab (8 rows)
#define VSLAB (DD*TT*HD)        // floats per (b,h) v slab
#define WPBH 392                // waves per bh (12544 rows / 32)
#define KMASK 0xFFFFFF00u
#define NEG_INF (-3.0e38f)

typedef float f4 __attribute__((ext_vector_type(4)));
typedef unsigned u4v __attribute__((ext_vector_type(4)));

__device__ __forceinline__ float readlane_f(float v, int l) {
    return __int_as_float(__builtin_amdgcn_readlane(__float_as_int(v), l));
}

__device__ __forceinline__ float wave_sum_u(float v) {
#define STEPS(ctrl) { float t_ = __int_as_float(__builtin_amdgcn_update_dpp( \
        0, __float_as_int(v), ctrl, 0xF, 0xF, true)); v += t_; }
    STEPS(0x111) STEPS(0x112) STEPS(0x114) STEPS(0x118) STEPS(0x142) STEPS(0x143)
#undef STEPS
    return readlane_f(v, 63);
}

// value part of a packed key (low 8 mantissa bits = idx, zeroed)
__device__ __forceinline__ float kval(float k) {
    return __uint_as_float(__float_as_uint(k) & KMASK);
}

// async HBM -> LDS, 16B per lane (R18-proven): staging never visits VGPRs.
__device__ __forceinline__ void gload_lds(const void* g, void* l) {
    __builtin_amdgcn_global_load_lds(
        (const __attribute__((address_space(1))) unsigned*)g,
        (__attribute__((address_space(3))) unsigned*)l, 16, 0, 0);
}

// Named members, NOT arrays (R5: arrays -> LDS; R4: refs -> scratch).
// FLOAT keys (R17-proven): idx masked into low mantissa bits preserves float
// order exactly; chain uses v_max/med3_f32, pack is and+or.
struct K6  { float k0,k1,k2,k3,k4,k5; };
struct K10 { float k0,k1,k2,k3,k4,k5,k6,k7,k8,k9; };
struct MR  { K10 f; float mx; };

// med3 sorted-insert (R13-proven): y0'=max(y0,c); yi'=med3(y_{i-1},y_i,c).
// depth-6 (R10-proven: loss ~2e-5 << threshold).
#define PUTK6(Q,X,D) { \
  unsigned cu_=(__float_as_uint(X)&KMASK)|(unsigned)(D); \
  float c_=__uint_as_float(cu_); \
  float n0_=fmaxf(Q.k0,c_); \
  float n1_=__builtin_amdgcn_fmed3f(Q.k0,Q.k1,c_); \
  float n2_=__builtin_amdgcn_fmed3f(Q.k1,Q.k2,c_); \
  float n3_=__builtin_amdgcn_fmed3f(Q.k2,Q.k3,c_); \
  float n4_=__builtin_amdgcn_fmed3f(Q.k3,Q.k4,c_); \
  float n5_=__builtin_amdgcn_fmed3f(Q.k4,Q.k5,c_); \
  Q.k0=n0_; Q.k1=n1_; Q.k2=n2_; Q.k3=n3_; Q.k4=n4_; Q.k5=n5_; }
#define PUT4K6(Q,V,D0) PUTK6(Q,(V).x,(D0)) PUTK6(Q,(V).y,(D0)+1) \
                       PUTK6(Q,(V).z,(D0)+2) PUTK6(Q,(V).w,(D0)+3)

// lane's chain over its eighth of row a (from LDS staging — the ONLY pattern
// with clean fetch; per-lane global streaming measured 1.75-1.89GB:
// R11/R14 eighth-chains, R15 contiguous half-rows)
__device__ __forceinline__ K6 chain_rows(const char* stg, int a, int b8) {
    K6 q = {NEG_INF,NEG_INF,NEG_INF,NEG_INF,NEG_INF,NEG_INF};
    const char* rb = stg + a*784 + b8*16;
    f4 v;
    v = *(const f4*)(rb);       PUT4K6(q, v, b8*4)
    v = *(const f4*)(rb+128);   PUT4K6(q, v, b8*4+32)
    v = *(const f4*)(rb+256);   PUT4K6(q, v, b8*4+64)
    v = *(const f4*)(rb+384);   PUT4K6(q, v, b8*4+96)
    v = *(const f4*)(rb+512);   PUT4K6(q, v, b8*4+128)
    v = *(const f4*)(rb+640);   PUT4K6(q, v, b8*4+160)
    if (b8 == 7) { f4 w = *(const f4*)(stg + a*784 + 768); PUT4K6(q, w, 192) }
    return q;
}

#define FSWZ(x, pat) __int_as_float(__builtin_amdgcn_ds_swizzle(__float_as_int(x), pat))
__device__ __forceinline__ K6 kshuf8_6(K6 a) {
    K6 r;
    r.k0=FSWZ(a.k0,0x201F); r.k1=FSWZ(a.k1,0x201F); r.k2=FSWZ(a.k2,0x201F);
    r.k3=FSWZ(a.k3,0x201F); r.k4=FSWZ(a.k4,0x201F); r.k5=FSWZ(a.k5,0x201F);
    return r;
}
__device__ __forceinline__ K10 kshuf16(K10 a) {
    K10 r;
    r.k0=FSWZ(a.k0,0x401F); r.k1=FSWZ(a.k1,0x401F); r.k2=FSWZ(a.k2,0x401F);
    r.k3=FSWZ(a.k3,0x401F); r.k4=FSWZ(a.k4,0x401F); r.k5=FSWZ(a.k5,0x401F);
    r.k6=FSWZ(a.k6,0x401F); r.k7=FSWZ(a.k7,0x401F); r.k8=FSWZ(a.k8,0x401F);
    r.k9=FSWZ(a.k9,0x401F);
    return r;
}
__device__ __forceinline__ float fbp(int bpx, float x) {
    return __int_as_float(__builtin_amdgcn_ds_bpermute(bpx, __float_as_int(x)));
}
__device__ __forceinline__ K10 kbp32(K10 a, int bpx) {
    K10 r;
    r.k0=fbp(bpx,a.k0); r.k1=fbp(bpx,a.k1); r.k2=fbp(bpx,a.k2);
    r.k3=fbp(bpx,a.k3); r.k4=fbp(bpx,a.k4); r.k5=fbp(bpx,a.k5);
    r.k6=fbp(bpx,a.k6); r.k7=fbp(bpx,a.k7); r.k8=fbp(bpx,a.k8);
    r.k9=fbp(bpx,a.k9);
    return r;
}

// merge two sorted-desc 6-lists -> sorted-desc top-10 of the 12-union.
__device__ __forceinline__ K10 kmrg66(K6 A, K6 B) {
    float p00=fminf(A.k0,B.k0);
    float p01=fminf(A.k0,B.k1), p10=fminf(A.k1,B.k0);
    float p02=fminf(A.k0,B.k2), p11=fminf(A.k1,B.k1), p20=fminf(A.k2,B.k0);
    float p03=fminf(A.k0,B.k3), p12=fminf(A.k1,B.k2), p21=fminf(A.k2,B.k1), p30=fminf(A.k3,B.k0);
    float p04=fminf(A.k0,B.k4), p13=fminf(A.k1,B.k3), p22=fminf(A.k2,B.k2), p31=fminf(A.k3,B.k1), p40=fminf(A.k4,B.k0);
    float p05=fminf(A.k0,B.k5), p14=fminf(A.k1,B.k4), p23=fminf(A.k2,B.k3), p32=fminf(A.k3,B.k2), p41=fminf(A.k4,B.k1), p50=fminf(A.k5,B.k0);
    float p15=fminf(A.k1,B.k5), p24=fminf(A.k2,B.k4), p33=fminf(A.k3,B.k3), p42=fminf(A.k4,B.k2), p51=fminf(A.k5,B.k1);
    float p25=fminf(A.k2,B.k5), p34=fminf(A.k3,B.k4), p43=fminf(A.k4,B.k3), p52=fminf(A.k5,B.k2);
    float p35=fminf(A.k3,B.k5), p44=fminf(A.k4,B.k4), p53=fminf(A.k5,B.k3);
    K10 M;
    M.k0=fmaxf(A.k0,B.k0);
    M.k1=fmaxf(fmaxf(A.k1,B.k1),p00);
    M.k2=fmaxf(fmaxf(A.k2,B.k2),fmaxf(p01,p10));
    M.k3=fmaxf(fmaxf(A.k3,B.k3),fmaxf(p02,fmaxf(p11,p20)));
    M.k4=fmaxf(fmaxf(A.k4,B.k4),fmaxf(fmaxf(p03,p12),fmaxf(p21,p30)));
    M.k5=fmaxf(fmaxf(A.k5,B.k5),fmaxf(fmaxf(p04,p13),fmaxf(p22,fmaxf(p31,p40))));
    M.k6=fmaxf(fmaxf(p05,p14),fmaxf(fmaxf(p23,p32),fmaxf(p41,p50)));
    M.k7=fmaxf(fmaxf(p15,p24),fmaxf(p33,fmaxf(p42,p51)));
    M.k8=fmaxf(fmaxf(p25,p34),fmaxf(p43,p52));
    M.k9=fmaxf(p35,fmaxf(p44,p53));
    return M;
}

// merge two sorted-desc 10-lists -> sorted-desc top-10 of union.
__device__ __forceinline__ K10 kmrg(K10 A, K10 B) {
    float p00=fminf(A.k0,B.k0);
    float p01=fminf(A.k0,B.k1), p10=fminf(A.k1,B.k0);
    float p02=fminf(A.k0,B.k2), p11=fminf(A.k1,B.k1), p20=fminf(A.k2,B.k0);
    float p03=fminf(A.k0,B.k3), p12=fminf(A.k1,B.k2), p21=fminf(A.k2,B.k1), p30=fminf(A.k3,B.k0);
    float p04=fminf(A.k0,B.k4), p13=fminf(A.k1,B.k3), p22=fminf(A.k2,B.k2), p31=fminf(A.k3,B.k1), p40=fminf(A.k4,B.k0);
    float p05=fminf(A.k0,B.k5), p14=fminf(A.k1,B.k4), p23=fminf(A.k2,B.k3), p32=fminf(A.k3,B.k2), p41=fminf(A.k4,B.k1), p50=fminf(A.k5,B.k0);
    float p06=fminf(A.k0,B.k6), p15=fminf(A.k1,B.k5), p24=fminf(A.k2,B.k4), p33=fminf(A.k3,B.k3), p42=fminf(A.k4,B.k2), p51=fminf(A.k5,B.k1), p60=fminf(A.k6,B.k0);
    float p07=fminf(A.k0,B.k7), p16=fminf(A.k1,B.k6), p25=fminf(A.k2,B.k5), p34=fminf(A.k3,B.k4), p43=fminf(A.k4,B.k3), p52=fminf(A.k5,B.k2), p61=fminf(A.k6,B.k1), p70=fminf(A.k7,B.k0);
    float p08=fminf(A.k0,B.k8), p17=fminf(A.k1,B.k7), p26=fminf(A.k2,B.k6), p35=fminf(A.k3,B.k5), p44=fminf(A.k4,B.k4), p53=fminf(A.k5,B.k3), p62=fminf(A.k6,B.k2), p71=fminf(A.k7,B.k1), p80=fminf(A.k8,B.k0);
    K10 M;
    M.k0=fmaxf(A.k0,B.k0);
    M.k1=fmaxf(fmaxf(A.k1,B.k1),p00);
    M.k2=fmaxf(fmaxf(A.k2,B.k2),fmaxf(p01,p10));
    M.k3=fmaxf(fmaxf(A.k3,B.k3),fmaxf(p02,fmaxf(p11,p20)));
    M.k4=fmaxf(fmaxf(A.k4,B.k4),fmaxf(fmaxf(p03,p12),fmaxf(p21,p30)));
    M.k5=fmaxf(fmaxf(A.k5,B.k5),fmaxf(fmaxf(p04,p13),fmaxf(p22,fmaxf(p31,p40))));
    M.k6=fmaxf(fmaxf(A.k6,B.k6),fmaxf(fmaxf(p05,p14),fmaxf(fmaxf(p23,p32),fmaxf(p41,p50))));
    M.k7=fmaxf(fmaxf(A.k7,B.k7),fmaxf(fmaxf(fmaxf(p06,p15),fmaxf(p24,p33)),fmaxf(fmaxf(p42,p51),p60)));
    M.k8=fmaxf(fmaxf(A.k8,B.k8),fmaxf(fmaxf(fmaxf(p07,p16),fmaxf(p25,p34)),fmaxf(fmaxf(p43,p52),fmaxf(p61,p70))));
    M.k9=fmaxf(fmaxf(A.k9,B.k9),fmaxf(fmaxf(fmaxf(p08,p17),fmaxf(p26,p35)),fmaxf(fmaxf(p44,p53),fmaxf(fmaxf(p62,p71),p80))));
    return M;
}

// eighth-chains -> row top-10 set + row max key
__device__ __forceinline__ MR merge_all(K6 q, int bpx) {
    K10 m = kmrg66(q, kshuf8_6(q));
    K10 n = kmrg(m, kshuf16(m));
    K10 r = kbp32(n, bpx);
    MR out;
    out.mx = fmaxf(n.k0, r.k0);
    out.f.k0=fmaxf(n.k0,r.k9); out.f.k1=fmaxf(n.k1,r.k8); out.f.k2=fmaxf(n.k2,r.k7);
    out.f.k3=fmaxf(n.k3,r.k6); out.f.k4=fmaxf(n.k4,r.k5); out.f.k5=fmaxf(n.k5,r.k4);
    out.f.k6=fmaxf(n.k6,r.k3); out.f.k7=fmaxf(n.k7,r.k2); out.f.k8=fmaxf(n.k8,r.k1);
    out.f.k9=fmaxf(n.k9,r.k0);
    return out;
}

// stage one 6272B sub-slab HBM -> LDS (7 async copies, no VGPR round trip)
#define STAGE(SRC) { const char* s_=(SRC); \
    gload_lds(s_ +         (size_t)lane*16, stg); \
    gload_lds(s_ + 1024 +  (size_t)lane*16, stg+1024); \
    gload_lds(s_ + 2048 +  (size_t)lane*16, stg+2048); \
    gload_lds(s_ + 3072 +  (size_t)lane*16, stg+3072); \
    gload_lds(s_ + 4096 +  (size_t)lane*16, stg+4096); \
    gload_lds(s_ + 5120 +  (size_t)lane*16, stg+5120); \
    if (lane < 8) gload_lds(s_ + 6144 + (size_t)lane*16, stg+6144); }
#define WAITV asm volatile("s_waitcnt vmcnt(0)" ::: "memory");

// pack (weight,f-idx): weight's low 8 mantissa bits replaced by the d-index
// (rel err 2^-16, R13-proven). Key K is a float key carrying idx in low bits.
#define PKW(F,K) ((__float_as_uint(F)&KMASK)|(__float_as_uint(K)&0xFFu))

__global__ __launch_bounds__(128) void vtop_main(
        const float* __restrict__ att_s, const float* __restrict__ att_t,
        const float* __restrict__ v_s,   const float* __restrict__ v_t,
        float* __restrict__ partial) {
    // per-wave private LDS (no barriers): 6272+2560 = 8832 B/wave
    __shared__ f4  stgv[WPB][SUB/16];
    __shared__ u4v wbuf[WPB][5][RPW];

    int tid  = threadIdx.x;
    int wid  = tid >> 6;
    int lane = tid & 63;
    char* stg = (char*)&stgv[wid][0];
    int a = lane & 7, b8 = lane >> 3;
    int bpx = (lane ^ 32) << 2;

    // XCD-aware bijective swizzle (nwg = 9408 = 8*1176 exactly) — R16-proven.
    int blk = (blockIdx.x % NXCD) * CPX + blockIdx.x / NXCD;
    int gwave = blk * WPB + wid;               // global wave id (0..18815)
    int bh = gwave / WPBH;

    const char* baseS = (const char*)att_s + (size_t)gwave * (RPW*DD*4);
    const char* baseT = (const char*)att_t + (size_t)gwave * (RPW*DD*4);

    STAGE(baseS)              // prologue: sub-slab 0 of S

#pragma unroll 1
    for (int s = 0; s < 4; ++s) {
        int row = (s << 3) | (lane & 7);       // this lane's row (valid lane<8)
        WAITV
        K6 qS = chain_rows(stg, a, b8);        // ds_reads all consumed here
        STAGE(baseT + s*SUB)                   // T latency hides under mergeS
        {
            MR mS = merge_all(qS, bpx);
            K10 fS = mS.f;
            float CS = kval(mS.mx);
            float wS0=__expf(kval(fS.k0)-CS), wS1=__expf(kval(fS.k1)-CS),
                  wS2=__expf(kval(fS.k2)-CS), wS3=__expf(kval(fS.k3)-CS),
                  wS4=__expf(kval(fS.k4)-CS), wS5=__expf(kval(fS.k5)-CS),
                  wS6=__expf(kval(fS.k6)-CS), wS7=__expf(kval(fS.k7)-CS),
                  wS8=__expf(kval(fS.k8)-CS), wS9=__expf(kval(fS.k9)-CS);
            float wsS = (((wS0+wS1)+(wS2+wS3))+((wS4+wS5)+(wS6+wS7)))+(wS8+wS9);
            float invS = __builtin_amdgcn_rcpf(wsS);
            // R19: store S results NOW -> fS/wS/invS die before chainT.
            // (R18 kept ~21 regs live across the T phase -> VGPR 68, just
            //  over the 64 occupancy cliff.)
            if (lane < 8) {
                u4v w;
                w.x=PKW(wS0*invS,fS.k0); w.y=PKW(wS1*invS,fS.k1);
                w.z=PKW(wS2*invS,fS.k2); w.w=PKW(wS3*invS,fS.k3);
                wbuf[wid][0][row]=w;
                w.x=PKW(wS4*invS,fS.k4); w.y=PKW(wS5*invS,fS.k5);
                w.z=PKW(wS6*invS,fS.k6); w.w=PKW(wS7*invS,fS.k7);
                wbuf[wid][1][row]=w;
                unsigned* h = (unsigned*)&wbuf[wid][2][row];
                h[0]=PKW(wS8*invS,fS.k8); h[1]=PKW(wS9*invS,fS.k9);
            }
        }

        WAITV
        K6 qT = chain_rows(stg, a, b8);
        if (s < 3) STAGE(baseS + (s+1)*SUB)    // next S hides under mergeT
        {
            MR mT = merge_all(qT, bpx);
            K10 fT = mT.f;
            float CT = kval(mT.mx);
            float wT0=__expf(kval(fT.k0)-CT), wT1=__expf(kval(fT.k1)-CT),
                  wT2=__expf(kval(fT.k2)-CT), wT3=__expf(kval(fT.k3)-CT),
                  wT4=__expf(kval(fT.k4)-CT), wT5=__expf(kval(fT.k5)-CT),
                  wT6=__expf(kval(fT.k6)-CT), wT7=__expf(kval(fT.k7)-CT),
                  wT8=__expf(kval(fT.k8)-CT), wT9=__expf(kval(fT.k9)-CT);
            float wsT = (((wT0+wT1)+(wT2+wT3))+((wT4+wT5)+(wT6+wT7)))+(wT8+wT9);
            float invT = -__builtin_amdgcn_rcpf(wsT);  // sign-fold
            if (lane < 8) {
                unsigned* h = (unsigned*)&wbuf[wid][2][row];
                h[2]=PKW(wT0*invT,fT.k0); h[3]=PKW(wT1*invT,fT.k1);
                u4v w;
                w.x=PKW(wT2*invT,fT.k2); w.y=PKW(wT3*invT,fT.k3);
                w.z=PKW(wT4*invT,fT.k4); w.w=PKW(wT5*invT,fT.k5);
                wbuf[wid][3][row]=w;
                w.x=PKW(wT6*invT,fT.k6); w.y=PKW(wT7*invT,fT.k7);
                w.z=PKW(wT8*invT,fT.k8); w.w=PKW(wT9*invT,fT.k9);
                wbuf[wid][4][row]=w;
            }
        }
    }

    // ---- wave-cooperative product: lane = output channel e ----
    // (w|idx) wave-uniform per row -> readfirstlane to SGPRs; weight rides an
    // SGPR fma operand, address math on SALU (R17-proven).
    const float* vSb = v_s + (size_t)bh * VSLAB;
    const float* vTb = v_t + (size_t)bh * VSLAB;
    unsigned ul = (unsigned)lane;
    float lacc = 0.f;
#pragma unroll 1
    for (int k = 0; k < RPW; ++k) {
        unsigned t64 = ((unsigned)(k & 7) << 6);
        const float* vSk = vSb + t64;
        const float* vTk = vTb + t64;
        u4v w0v=wbuf[wid][0][k], w1v=wbuf[wid][1][k], w2v=wbuf[wid][2][k],
            w3v=wbuf[wid][3][k], w4v=wbuf[wid][4][k];
        float d0=0.f, d1=0.f, d2=0.f, d3=0.f;   // 4-way split: 5-deep chains
#define TRM(U, VB, ACC) { unsigned pk_=(unsigned)__builtin_amdgcn_readfirstlane((int)(U)); \
        float wf_ = __uint_as_float(pk_ & KMASK); \
        ACC = fmaf(wf_, VB[((pk_ & 0xFFu) << 9) + ul], ACC); }
        TRM(w0v.x, vSk, d0) TRM(w0v.y, vSk, d1) TRM(w0v.z, vSk, d2) TRM(w0v.w, vSk, d3)
        TRM(w1v.x, vSk, d0) TRM(w1v.y, vSk, d1) TRM(w1v.z, vSk, d2) TRM(w1v.w, vSk, d3)
        TRM(w2v.x, vSk, d0) TRM(w2v.y, vSk, d1)                     // S8,S9
        TRM(w2v.z, vTk, d2) TRM(w2v.w, vTk, d3)                     // T0,T1
        TRM(w3v.x, vTk, d0) TRM(w3v.y, vTk, d1) TRM(w3v.z, vTk, d2) TRM(w3v.w, vTk, d3)
        TRM(w4v.x, vTk, d0) TRM(w4v.y, vTk, d1) TRM(w4v.z, vTk, d2) TRM(w4v.w, vTk, d3)
#undef TRM
        float dsum = (d0 + d1) + (d2 + d3);
        lacc = fmaf(dsum, dsum, lacc);
    }

    float tot = wave_sum_u(lacc);
    if (lane == 0) partial[gwave] = tot;
}

// stage 1: 74 blocks x 256 -> 74 partials
__global__ __launch_bounds__(256) void vtop_reduce1(
        const float* __restrict__ partial, float* __restrict__ p2) {
    int i = blockIdx.x * 256 + threadIdx.x;
    float v = (i < NPART) ? partial[i] : 0.f;
    float wtot = wave_sum_u(v);
    __shared__ float sm[4];
    int lane = threadIdx.x & 63, wid = threadIdx.x >> 6;
    if (lane == 0) sm[wid] = wtot;
    __syncthreads();
    if (threadIdx.x == 0) p2[blockIdx.x] = (sm[0] + sm[1]) + (sm[2] + sm[3]);
}

// stage 2: single block over 74 values
__global__ __launch_bounds__(256) void vtop_reduce2(
        const float* __restrict__ p2, float* __restrict__ out) {
    __shared__ double smd[256];
    double a = 0.0;
    if (threadIdx.x < NRED1) a = (double)p2[threadIdx.x];
    smd[threadIdx.x] = a;
    __syncthreads();
    for (int s = 128; s > 0; s >>= 1) {
        if (threadIdx.x < s) smd[threadIdx.x] += smd[threadIdx.x + s];
        __syncthreads();
    }
    if (threadIdx.x == 0) {
        const double inv_n = 1.0 / ((double)NBH * PP * TT * HD);  // 1/38535168
        out[0] = (float)(smd[0] * inv_n);
    }
}

extern "C" void kernel_launch(void* const* d_in, const int* in_sizes, int n_in,
                              void* d_out, int out_size, void* d_ws, size_t ws_size,
                              hipStream_t stream) {
    const float* att_s = (const float*)d_in[0];
    const float* att_t = (const float*)d_in[1];
    const float* v_s   = (const float*)d_in[2];
    const float* v_t   = (const float*)d_in[3];
    float* out     = (float*)d_out;
    float* partial = (float*)d_ws;                 // NPART floats (~75 KB)
    float* p2      = (float*)d_ws + NPART;         // NRED1 floats

    vtop_main<<<NBLK5, 128, 0, stream>>>(att_s, att_t, v_s, v_t, partial);
    vtop_reduce1<<<NRED1, 256, 0, stream>>>(partial, p2);
    vtop_reduce2<<<1, 256, 0, stream>>>(p2, out);
}